// Round 1
// baseline (937.746 us; speedup 1.0000x reference)
//
#include <hip/hip_runtime.h>
#include <hip/hip_bf16.h>
#include <math.h>

// Problem constants (match reference)
#define BB 16
#define NN 2048
#define DD 512
#define MM 512

// GEMM tiling: 128x64 output tile per 256-thread block, k-chunk 32.
// Micro-tile 8x4 per thread: 32 FMA per (2+1) ds_read_b128 -> decent VALU util.
#define TM 128
#define TN 64
#define TKc 32

__device__ __forceinline__ float gelu_f(float x) {
  // jax.nn.gelu default (approximate=True, tanh form)
  float x3 = x * x * x;
  return 0.5f * x * (1.0f + tanhf(0.79788456080286536f * (x + 0.044715f * x3)));
}

// Block-wide LayerNorm stats over 512 elements (256 threads x 2 each).
__device__ __forceinline__ void ln_stats_512(float sum, float sq, float& mu, float& inv_std) {
  #pragma unroll
  for (int off = 32; off >= 1; off >>= 1) {
    sum += __shfl_down(sum, off);
    sq  += __shfl_down(sq,  off);
  }
  __shared__ float red[8];
  __shared__ float mv[2];
  const int lane = threadIdx.x & 63;
  const int wid  = threadIdx.x >> 6;
  if (lane == 0) { red[wid] = sum; red[4 + wid] = sq; }
  __syncthreads();
  if (threadIdx.x == 0) {
    float ts = red[0] + red[1] + red[2] + red[3];
    float tq = red[4] + red[5] + red[6] + red[7];
    float m = ts * (1.0f / 512.0f);
    float v = tq * (1.0f / 512.0f) - m * m;
    mv[0] = m;
    mv[1] = rsqrtf(v + 1e-5f);
  }
  __syncthreads();
  mu = mv[0];
  inv_std = mv[1];
}

// ---------------------------------------------------------------------------
// Step 1: field[b,m,:] = sum_n exp(-(grid_m - pos_bn)^2 / (2 sigma^2)) * emb[b,n,:]
// Batched GEMM with the K-tile computed on the fly (exp is ~40us of VALU total).
// grid: (MM/TM, DD/TN, BB), block 256
// ---------------------------------------------------------------------------
__global__ __launch_bounds__(256) void rbf_gemm_kernel(
    const float* __restrict__ emb, const float* __restrict__ pos,
    const float* __restrict__ sigma, float* __restrict__ field)
{
  __shared__ float Ks[TKc][TM + 4];  // +4 pad: break bank aliasing on writes
  __shared__ float Es[TKc][TN];

  const int b  = blockIdx.z;
  const int m0 = blockIdx.x * TM;
  const int c0 = blockIdx.y * TN;
  const int tid = threadIdx.x;
  const int tx = tid & 15;   // col group (4 cols)
  const int ty = tid >> 4;   // row group (8 rows)

  const float s = sigma[0];
  const float inv2s2 = 1.0f / (2.0f * s * s);
  const float inv511 = 1.0f / 511.0f;

  float acc[8][4];
  #pragma unroll
  for (int i = 0; i < 8; ++i)
    #pragma unroll
    for (int j = 0; j < 4; ++j) acc[i][j] = 0.0f;

  const int nlane = tid & 31;  // n within chunk (fixed per thread)
  const int mbase = tid >> 5;  // 0..7

  for (int nc = 0; nc < NN; nc += TKc) {
    // --- K tile: Ks[n][m], 128*32 values, 16 per thread ---
    const float p = pos[(size_t)b * NN + nc + nlane];
    #pragma unroll
    for (int q = 0; q < 16; ++q) {
      const int m = q * 8 + mbase;
      const float g = (float)(m0 + m) * inv511;
      const float d = g - p;
      Ks[nlane][m] = __expf(-inv2s2 * d * d);
    }
    // --- E tile: Es[n][c], 32x64 ---
    #pragma unroll
    for (int q = 0; q < 2; ++q) {
      const int n = (tid >> 4) + q * 16;
      const int c = (tid & 15) << 2;
      const float4 v = *(const float4*)(emb + ((size_t)b * NN + nc + n) * DD + c0 + c);
      *(float4*)&Es[n][c] = v;
    }
    __syncthreads();

    #pragma unroll
    for (int kk = 0; kk < TKc; ++kk) {
      const float4* ap = (const float4*)&Ks[kk][ty * 8];
      const float4 a0 = ap[0];
      const float4 a1 = ap[1];
      const float4 bv = *(const float4*)&Es[kk][tx * 4];
      const float a[8] = {a0.x, a0.y, a0.z, a0.w, a1.x, a1.y, a1.z, a1.w};
      const float bb[4] = {bv.x, bv.y, bv.z, bv.w};
      #pragma unroll
      for (int i = 0; i < 8; ++i)
        #pragma unroll
        for (int j = 0; j < 4; ++j) acc[i][j] += a[i] * bb[j];
    }
    __syncthreads();
  }

  #pragma unroll
  for (int i = 0; i < 8; ++i) {
    const int m = m0 + ty * 8 + i;
    float4 v = make_float4(acc[i][0], acc[i][1], acc[i][2], acc[i][3]);
    *(float4*)(field + ((size_t)b * MM + m) * DD + c0 + tx * 4) = v;
  }
}

// ---------------------------------------------------------------------------
// Step 2a: mix[b,m,h*64+j] = sum_k alpha[h,k] * field[b,m,k*64+j]
// one block per (b,m) row
// ---------------------------------------------------------------------------
__global__ __launch_bounds__(256) void mix_kernel(
    const float* __restrict__ field, const float* __restrict__ alpha,
    float* __restrict__ mixout)
{
  __shared__ float row[DD];
  __shared__ float al[64];
  const size_t r = blockIdx.x;
  const int t = threadIdx.x;
  const float* fr = field + r * DD;
  *(float2*)&row[t * 2] = *(const float2*)&fr[t * 2];
  if (t < 64) al[t] = alpha[t];
  __syncthreads();
  const int j = t * 2;
  const int h = j >> 6;       // j even, so j and j+1 share h
  const int jj = j & 63;
  float s0 = 0.0f, s1 = 0.0f;
  #pragma unroll
  for (int k = 0; k < 8; ++k) {
    const float a = al[h * 8 + k];
    const float2 v = *(const float2*)&row[k * 64 + jj];
    s0 += a * v.x;
    s1 += a * v.y;
  }
  *(float2*)&mixout[r * DD + j] = make_float2(s0, s1);
}

// ---------------------------------------------------------------------------
// Generic D=512 GEMM: C = maybe_gelu(A @ W + bias) + (res ? res : 0)
// A: [R,512], W: [512,512], grid (R/TM, DD/TN), block 256
// ---------------------------------------------------------------------------
template <int ACT>
__global__ __launch_bounds__(256) void gemm512_kernel(
    const float* __restrict__ A, const float* __restrict__ W,
    const float* __restrict__ bias, const float* __restrict__ res,
    float* __restrict__ C)
{
  __shared__ float As[TKc][TM + 4];
  __shared__ float Ws[TKc][TN];

  const int r0 = blockIdx.x * TM;
  const int c0 = blockIdx.y * TN;
  const int tid = threadIdx.x;
  const int tx = tid & 15;
  const int ty = tid >> 4;

  float acc[8][4];
  #pragma unroll
  for (int i = 0; i < 8; ++i)
    #pragma unroll
    for (int j = 0; j < 4; ++j) acc[i][j] = 0.0f;

  for (int kc = 0; kc < DD; kc += TKc) {
    // A tile: 128 rows x 32 k, 4 float4 per thread (transposed store)
    #pragma unroll
    for (int p = 0; p < 4; ++p) {
      const int row = (tid >> 3) + p * 32;
      const int k4 = (tid & 7) << 2;
      const float4 v = *(const float4*)(A + (size_t)(r0 + row) * DD + kc + k4);
      As[k4 + 0][row] = v.x;
      As[k4 + 1][row] = v.y;
      As[k4 + 2][row] = v.z;
      As[k4 + 3][row] = v.w;
    }
    // W tile: 32 k x 64 cols
    #pragma unroll
    for (int q = 0; q < 2; ++q) {
      const int k = (tid >> 4) + q * 16;
      const int c = (tid & 15) << 2;
      const float4 v = *(const float4*)(W + (size_t)(kc + k) * DD + c0 + c);
      *(float4*)&Ws[k][c] = v;
    }
    __syncthreads();

    #pragma unroll
    for (int kk = 0; kk < TKc; ++kk) {
      const float4* ap = (const float4*)&As[kk][ty * 8];
      const float4 a0 = ap[0];
      const float4 a1 = ap[1];
      const float4 bv = *(const float4*)&Ws[kk][tx * 4];
      const float a[8] = {a0.x, a0.y, a0.z, a0.w, a1.x, a1.y, a1.z, a1.w};
      const float bb[4] = {bv.x, bv.y, bv.z, bv.w};
      #pragma unroll
      for (int i = 0; i < 8; ++i)
        #pragma unroll
        for (int j = 0; j < 4; ++j) acc[i][j] += a[i] * bb[j];
    }
    __syncthreads();
  }

  const float4 bsv = *(const float4*)(bias + c0 + tx * 4);
  #pragma unroll
  for (int i = 0; i < 8; ++i) {
    const int row = r0 + ty * 8 + i;
    const int col = c0 + tx * 4;
    float4 v;
    v.x = acc[i][0] + bsv.x;
    v.y = acc[i][1] + bsv.y;
    v.z = acc[i][2] + bsv.z;
    v.w = acc[i][3] + bsv.w;
    if (ACT == 1) {
      v.x = gelu_f(v.x); v.y = gelu_f(v.y); v.z = gelu_f(v.z); v.w = gelu_f(v.w);
    }
    if (res != nullptr) {
      const float4 rv = *(const float4*)(res + (size_t)row * DD + col);
      v.x += rv.x; v.y += rv.y; v.z += rv.z; v.w += rv.w;
    }
    *(float4*)(C + (size_t)row * DD + col) = v;
  }
}

// ---------------------------------------------------------------------------
// One explicit-Euler diffusion step along M (Neumann / edge-pad boundary).
// out = f + dt*coef_d*(f[m-1] - 2f + f[m+1]); layout [B,M,D], m-stride = D
// ---------------------------------------------------------------------------
__global__ __launch_bounds__(256) void diffuse_kernel(
    const float* __restrict__ in, float* __restrict__ out,
    const float* __restrict__ coef)
{
  const size_t i4 = (size_t)blockIdx.x * 256 + threadIdx.x;
  const size_t base = i4 * 4;
  const int d = (int)(base & (DD - 1));
  const int m = (int)((base >> 9) & (MM - 1));
  const float4 f = *(const float4*)(in + base);
  const float4 fm = (m > 0)      ? *(const float4*)(in + base - DD) : f;
  const float4 fp = (m < MM - 1) ? *(const float4*)(in + base + DD) : f;
  const float4 c = *(const float4*)(coef + d);
  float4 o;
  o.x = f.x + 0.01f * c.x * (fm.x - 2.0f * f.x + fp.x);
  o.y = f.y + 0.01f * c.y * (fm.y - 2.0f * f.y + fp.y);
  o.z = f.z + 0.01f * c.z * (fm.z - 2.0f * f.z + fp.z);
  o.w = f.w + 0.01f * c.w * (fm.w - 2.0f * f.w + fp.w);
  *(float4*)(out + base) = o;
}

// ---------------------------------------------------------------------------
// Step 6+7a: linear sampling at token positions + residual + LayerNorm1 -> enh
// one block per (b,n) token
// ---------------------------------------------------------------------------
__global__ __launch_bounds__(256) void sample_ln_kernel(
    const float* __restrict__ field, const float* __restrict__ pos,
    const float* __restrict__ emb, const float* __restrict__ g,
    const float* __restrict__ be, float* __restrict__ enh)
{
  const size_t row = blockIdx.x;       // b*N + n
  const int b = (int)(row >> 11);      // N = 2048
  const int t = threadIdx.x;

  const float p = pos[row];
  const float u = fminf(fmaxf(p, 0.0f), 1.0f) * 511.0f;
  int i0 = (int)floorf(u);
  if (i0 > MM - 2) i0 = MM - 2;
  if (i0 < 0) i0 = 0;
  const float w = u - (float)i0;

  const float* f0 = field + ((size_t)b * MM + i0) * DD;
  const int j = t * 2;
  const float2 a0 = *(const float2*)(f0 + j);
  const float2 a1 = *(const float2*)(f0 + DD + j);
  const float2 e  = *(const float2*)(emb + row * DD + j);
  const float sx = (1.0f - w) * a0.x + w * a1.x + e.x;
  const float sy = (1.0f - w) * a0.y + w * a1.y + e.y;

  float mu, is;
  ln_stats_512(sx + sy, sx * sx + sy * sy, mu, is);

  const float2 gg = *(const float2*)(g + j);
  const float2 bb2 = *(const float2*)(be + j);
  float2 o;
  o.x = (sx - mu) * is * gg.x + bb2.x;
  o.y = (sy - mu) * is * gg.y + bb2.y;
  *(float2*)&enh[row * DD + j] = o;
}

// ---------------------------------------------------------------------------
// Step 7b: in-place LayerNorm over d_out rows (input already = out_tmp + enh)
// ---------------------------------------------------------------------------
__global__ __launch_bounds__(256) void ln2_kernel(
    float* __restrict__ out, const float* __restrict__ g,
    const float* __restrict__ be)
{
  const size_t row = blockIdx.x;
  const int t = threadIdx.x;
  const int j = t * 2;
  const float2 x = *(const float2*)(out + row * DD + j);

  float mu, is;
  ln_stats_512(x.x + x.y, x.x * x.x + x.y * x.y, mu, is);

  const float2 gg = *(const float2*)(g + j);
  const float2 bb2 = *(const float2*)(be + j);
  float2 o;
  o.x = (x.x - mu) * is * gg.x + bb2.x;
  o.y = (x.y - mu) * is * gg.y + bb2.y;
  *(float2*)(out + row * DD + j) = o;
}

// ---------------------------------------------------------------------------

extern "C" void kernel_launch(void* const* d_in, const int* in_sizes, int n_in,
                              void* d_out, int out_size, void* d_ws, size_t ws_size,
                              hipStream_t stream)
{
  const float* emb   = (const float*)d_in[0];
  const float* pos   = (const float*)d_in[1];
  const float* sigma = (const float*)d_in[2];
  const float* alpha = (const float*)d_in[3];
  const float* w_int = (const float*)d_in[4];
  const float* b_int = (const float*)d_in[5];
  const float* diffc = (const float*)d_in[6];
  const float* W1    = (const float*)d_in[7];
  const float* b1    = (const float*)d_in[8];
  const float* W2    = (const float*)d_in[9];
  const float* b2    = (const float*)d_in[10];
  const float* evoc  = (const float*)d_in[11];
  const float* ln1g  = (const float*)d_in[12];
  const float* ln1b  = (const float*)d_in[13];
  const float* Wout  = (const float*)d_in[14];
  const float* bout  = (const float*)d_in[15];
  const float* ln2g  = (const float*)d_in[16];
  const float* ln2b  = (const float*)d_in[17];

  float* out = (float*)d_out;
  float* ws0 = (float*)d_ws;                        // field ping [B,M,D]
  float* ws1 = ws0 + (size_t)BB * MM * DD;          // field pong [B,M,D]
  float* ws2 = ws1 + (size_t)BB * MM * DD;          // enh [B,N,D]

  const dim3 blk(256);
  const dim3 gemm_field(BB * MM / TM, DD / TN);     // (64, 8)
  const dim3 gemm_tok(BB * NN / TM, DD / TN);       // (256, 8)
  const int diff_blocks = BB * MM * DD / 4 / 256;   // 4096

  // 1) RBF projection -> ws0
  rbf_gemm_kernel<<<dim3(MM / TM, DD / TN, BB), blk, 0, stream>>>(emb, pos, sigma, ws0);
  // 2) head mix -> ws1; field = field + mix@w_int + b_int -> ws0
  mix_kernel<<<dim3(BB * MM), blk, 0, stream>>>(ws0, alpha, ws1);
  gemm512_kernel<0><<<gemm_field, blk, 0, stream>>>(ws1, w_int, b_int, ws0, ws0);
  // 3) diffusion x3 (diff_coef): ws0 -> ws1 -> ws0 -> ws1
  diffuse_kernel<<<dim3(diff_blocks), blk, 0, stream>>>(ws0, ws1, diffc);
  diffuse_kernel<<<dim3(diff_blocks), blk, 0, stream>>>(ws1, ws0, diffc);
  diffuse_kernel<<<dim3(diff_blocks), blk, 0, stream>>>(ws0, ws1, diffc);
  // 4) gated MLP: H = gelu(field@W1+b1) -> ws0 ; field = H@W2 + b2 + field -> ws1
  gemm512_kernel<1><<<gemm_field, blk, 0, stream>>>(ws1, W1, b1, nullptr, ws0);
  gemm512_kernel<0><<<gemm_field, blk, 0, stream>>>(ws0, W2, b2, ws1, ws1);
  // 5) diffusion x3 (evo_coef): ws1 -> ws0 -> ws1 -> ws0
  diffuse_kernel<<<dim3(diff_blocks), blk, 0, stream>>>(ws1, ws0, evoc);
  diffuse_kernel<<<dim3(diff_blocks), blk, 0, stream>>>(ws0, ws1, evoc);
  diffuse_kernel<<<dim3(diff_blocks), blk, 0, stream>>>(ws1, ws0, evoc);
  // 6+7a) sample + residual + LN1 -> ws2 (enh)
  sample_ln_kernel<<<dim3(BB * NN), blk, 0, stream>>>(ws0, pos, emb, ln1g, ln1b, ws2);
  // 7b) d_out = enh@Wout + bout + enh ; LN2 in place
  gemm512_kernel<0><<<gemm_tok, blk, 0, stream>>>(ws2, Wout, bout, ws2, out);
  ln2_kernel<<<dim3(BB * NN), blk, 0, stream>>>(out, ln2g, ln2b);
}

// Round 2
// 433.862 us; speedup vs baseline: 2.1614x; 2.1614x over previous
//
#include <hip/hip_runtime.h>
#include <hip/hip_bf16.h>
#include <math.h>

#define BB 16
#define NN 2048
#define DD 512
#define MM 512

typedef __attribute__((ext_vector_type(8))) short bf16x8;
typedef __attribute__((ext_vector_type(4))) float f32x4;

__device__ __forceinline__ short f2b(float x) {
  union { __hip_bfloat16 h; short s; } u; u.h = __float2bfloat16(x); return u.s;
}
__device__ __forceinline__ float b2f(short s) {
  union { short s2; __hip_bfloat16 h; } u; u.s2 = s; return __bfloat162float(u.h);
}
__device__ __forceinline__ float gelu_f(float x) {
  float x3 = x * x * x;
  return 0.5f * x * (1.0f + tanhf(0.79788456080286536f * (x + 0.044715f * x3)));
}

// ---------------------------------------------------------------------------
// Generic bf16 MFMA GEMM: C[row][col] = act(A@B + bias) + res
// A: [R][K] bf16 row-major (or RBF kernel matrix computed on the fly)
// BT: [Ncols][K] bf16 (B transposed so fragments are k-contiguous)
// mfma_f32_16x16x32_bf16 layout:
//   A/B frag: idx = lane&15, k = (lane>>4)*8 + 0..7
//   C/D frag: col = lane&15, row = (lane>>4)*4 + reg     [verified m89/m91]
// For RBF: `sigp` points at sigma (device scalar), pos at positions[b].
// ---------------------------------------------------------------------------
template<int BM, int WR, int WC, int ACT, int RES, bool BIAS, bool WB32, bool WB16, bool RBF>
__global__ __launch_bounds__(256) void gemm_mfma(
    const short* __restrict__ A, const short* __restrict__ BT,
    const float* __restrict__ bias, const void* __restrict__ res,
    float* __restrict__ C, short* __restrict__ Cb,
    const float* __restrict__ pos, const float* __restrict__ sigp, int K)
{
  constexpr int BN = 128;
  constexpr int CA = BM / 16;
  constexpr int MF = BM / WR / 16;
  constexpr int NF = BN / WC / 16;
  constexpr int WMT = BM / WR;
  constexpr int WNT = BN / WC;

  __shared__ short As[BM * 32];
  __shared__ short Bs[BN * 32];

  const int tid = threadIdx.x;
  const int wid = tid >> 6, lane = tid & 63;
  const int lrow = lane & 15, kg = lane >> 4;
  const int wr = (WR == 1) ? 0 : (wid >> 1);
  const int wc = (WR == 1) ? wid : (wid & 1);
  const int r0 = blockIdx.x * BM;
  const int c0 = blockIdx.y * BN;
  const int z = blockIdx.z;

  const size_t zBT = RBF ? (size_t)z * DD * NN : 0;
  const size_t zC  = RBF ? (size_t)z * MM * DD : 0;

  float inv2s2 = 0.0f, gval = 0.0f;
  if constexpr (RBF) {
    const float s = sigp[0];
    inv2s2 = 1.0f / (2.0f * s * s);
    gval = (float)(r0 + (tid >> 2)) * (1.0f / 511.0f);
  }

  f32x4 acc[MF][NF];
  #pragma unroll
  for (int m = 0; m < MF; ++m)
    #pragma unroll
    for (int n = 0; n < NF; ++n) acc[m][n] = (f32x4){0.f, 0.f, 0.f, 0.f};

  for (int kc = 0; kc < K; kc += 32) {
    #pragma unroll
    for (int i = 0; i < 2; ++i) {
      const int ch = wid * 2 + i;
      const int col = ch * 16 + (lane >> 2);
      const short* gp = BT + zBT + (size_t)(c0 + col) * K + kc + (lane & 3) * 8;
      __builtin_amdgcn_global_load_lds(
          (const __attribute__((address_space(1))) void*)gp,
          (__attribute__((address_space(3))) void*)&Bs[ch * 512], 16, 0, 0);
    }
    if constexpr (RBF) {
      const int m = tid >> 2, ng = tid & 3;
      const float* pp = pos + (size_t)z * NN + kc + ng * 8;
      const float4 p0 = *(const float4*)pp;
      const float4 p1 = *(const float4*)(pp + 4);
      const float pv[8] = {p0.x, p0.y, p0.z, p0.w, p1.x, p1.y, p1.z, p1.w};
      bf16x8 o;
      #pragma unroll
      for (int j = 0; j < 8; ++j) {
        const float d = gval - pv[j];
        o[j] = f2b(__expf(-(d * d) * inv2s2));
      }
      *(bf16x8*)&As[m * 32 + ng * 8] = o;
    } else {
      #pragma unroll
      for (int i = 0; i < CA / 4; ++i) {
        const int ch = wid * (CA / 4) + i;
        const int row = ch * 16 + (lane >> 2);
        const short* gp = A + (size_t)(r0 + row) * K + kc + (lane & 3) * 8;
        __builtin_amdgcn_global_load_lds(
            (const __attribute__((address_space(1))) void*)gp,
            (__attribute__((address_space(3))) void*)&As[ch * 512], 16, 0, 0);
      }
    }
    __syncthreads();

    bf16x8 af[MF], bfv[NF];
    #pragma unroll
    for (int m = 0; m < MF; ++m)
      af[m] = *(const bf16x8*)&As[(wr * WMT + m * 16 + lrow) * 32 + kg * 8];
    #pragma unroll
    for (int n = 0; n < NF; ++n)
      bfv[n] = *(const bf16x8*)&Bs[(wc * WNT + n * 16 + lrow) * 32 + kg * 8];
    #pragma unroll
    for (int m = 0; m < MF; ++m)
      #pragma unroll
      for (int n = 0; n < NF; ++n)
        acc[m][n] = __builtin_amdgcn_mfma_f32_16x16x32_bf16(af[m], bfv[n], acc[m][n], 0, 0, 0);
    __syncthreads();
  }

  #pragma unroll
  for (int m = 0; m < MF; ++m) {
    #pragma unroll
    for (int n = 0; n < NF; ++n) {
      const int col = c0 + wc * WNT + n * 16 + lrow;
      const int row0 = r0 + wr * WMT + m * 16 + kg * 4;
      float bi = 0.0f;
      if constexpr (BIAS) bi = bias[col];
      #pragma unroll
      for (int r = 0; r < 4; ++r) {
        float x = acc[m][n][r] + bi;
        if constexpr (ACT == 1) x = gelu_f(x);
        const size_t off = zC + (size_t)(row0 + r) * DD + col;
        if constexpr (RES == 1) x += ((const float*)res)[off];
        if constexpr (RES == 2) x += b2f(((const short*)res)[off]);
        if constexpr (WB32) C[off] = x;
        if constexpr (WB16) Cb[off] = f2b(x);
      }
    }
  }
}

// ---------------------------------------------------------------------------
// Transpose + fp32->bf16 for the four 512x512 weights: WT[c][k] = W[k][c]
// ---------------------------------------------------------------------------
__global__ __launch_bounds__(256) void wtrans_kernel(
    const float* __restrict__ w0, const float* __restrict__ w1,
    const float* __restrict__ w2, const float* __restrict__ w3,
    short* __restrict__ outW)
{
  __shared__ float tle[32][33];
  const int z = blockIdx.z;
  const float* W = (z == 0) ? w0 : (z == 1) ? w1 : (z == 2) ? w2 : w3;
  short* WT = outW + (size_t)z * DD * DD;
  const int bx = blockIdx.x * 32;
  const int by = blockIdx.y * 32;
  const int t = threadIdx.x;
  const int r = t >> 3, c4 = (t & 7) * 4;
  const float4 v = *(const float4*)(W + (size_t)(bx + r) * DD + by + c4);
  tle[r][c4 + 0] = v.x; tle[r][c4 + 1] = v.y; tle[r][c4 + 2] = v.z; tle[r][c4 + 3] = v.w;
  __syncthreads();
  const short4 o = make_short4(f2b(tle[c4 + 0][r]), f2b(tle[c4 + 1][r]),
                               f2b(tle[c4 + 2][r]), f2b(tle[c4 + 3][r]));
  *(short4*)(WT + (size_t)(by + r) * DD + bx + c4) = o;
}

// emb [b][n][d] fp32 -> embT [b][d][n] bf16
__global__ __launch_bounds__(256) void embtrans_kernel(
    const float* __restrict__ emb, short* __restrict__ embT)
{
  __shared__ float tle[32][33];
  const int z = blockIdx.z;
  const int bx = blockIdx.x * 32;  // n tile
  const int by = blockIdx.y * 32;  // d tile
  const int t = threadIdx.x;
  const int r = t >> 3, c4 = (t & 7) * 4;
  const float4 v = *(const float4*)(emb + ((size_t)z * NN + bx + r) * DD + by + c4);
  tle[r][c4 + 0] = v.x; tle[r][c4 + 1] = v.y; tle[r][c4 + 2] = v.z; tle[r][c4 + 3] = v.w;
  __syncthreads();
  const short4 o = make_short4(f2b(tle[c4 + 0][r]), f2b(tle[c4 + 1][r]),
                               f2b(tle[c4 + 2][r]), f2b(tle[c4 + 3][r]));
  *(short4*)(embT + ((size_t)z * DD + by + r) * NN + bx + c4) = o;
}

// ---------------------------------------------------------------------------
// head mix -> bf16
// ---------------------------------------------------------------------------
__global__ __launch_bounds__(256) void mix_kernel(
    const float* __restrict__ field, const float* __restrict__ alpha,
    short* __restrict__ mixout)
{
  __shared__ float row[DD];
  __shared__ float al[64];
  const size_t r = blockIdx.x;
  const int t = threadIdx.x;
  const float* fr = field + r * DD;
  *(float2*)&row[t * 2] = *(const float2*)&fr[t * 2];
  if (t < 64) al[t] = alpha[t];
  __syncthreads();
  const int j = t * 2;
  const int h = j >> 6;
  const int jj = j & 63;
  float s0 = 0.0f, s1 = 0.0f;
  #pragma unroll
  for (int k = 0; k < 8; ++k) {
    const float a = al[h * 8 + k];
    const float2 v = *(const float2*)&row[k * 64 + jj];
    s0 += a * v.x;
    s1 += a * v.y;
  }
  *(short2*)&mixout[r * DD + j] = make_short2(f2b(s0), f2b(s1));
}

// ---------------------------------------------------------------------------
// One diffusion step; optional bf16 copy of the output
// ---------------------------------------------------------------------------
template<bool WB16>
__global__ __launch_bounds__(256) void diffuse_kernel(
    const float* __restrict__ in, float* __restrict__ out,
    const float* __restrict__ coef, short* __restrict__ bfout)
{
  const size_t base = ((size_t)blockIdx.x * 256 + threadIdx.x) * 4;
  const int d = (int)(base & (DD - 1));
  const int m = (int)((base >> 9) & (MM - 1));
  const float4 f = *(const float4*)(in + base);
  const float4 fm = (m > 0) ? *(const float4*)(in + base - DD) : f;
  const float4 fp = (m < MM - 1) ? *(const float4*)(in + base + DD) : f;
  const float4 c = *(const float4*)(coef + d);
  float4 o;
  o.x = f.x + 0.01f * c.x * (fm.x - 2.0f * f.x + fp.x);
  o.y = f.y + 0.01f * c.y * (fm.y - 2.0f * f.y + fp.y);
  o.z = f.z + 0.01f * c.z * (fm.z - 2.0f * f.z + fp.z);
  o.w = f.w + 0.01f * c.w * (fm.w - 2.0f * f.w + fp.w);
  *(float4*)(out + base) = o;
  if constexpr (WB16) {
    *(short4*)(bfout + base) = make_short4(f2b(o.x), f2b(o.y), f2b(o.z), f2b(o.w));
  }
}

// ---------------------------------------------------------------------------
// LN helpers / sampling
// ---------------------------------------------------------------------------
__device__ __forceinline__ void ln_stats_512(float sum, float sq, float& mu, float& inv_std) {
  #pragma unroll
  for (int off = 32; off >= 1; off >>= 1) {
    sum += __shfl_down(sum, off);
    sq  += __shfl_down(sq,  off);
  }
  __shared__ float red[8];
  __shared__ float mv[2];
  const int lane = threadIdx.x & 63;
  const int wid = threadIdx.x >> 6;
  if (lane == 0) { red[wid] = sum; red[4 + wid] = sq; }
  __syncthreads();
  if (threadIdx.x == 0) {
    float ts = red[0] + red[1] + red[2] + red[3];
    float tq = red[4] + red[5] + red[6] + red[7];
    float m = ts * (1.0f / 512.0f);
    float v = tq * (1.0f / 512.0f) - m * m;
    mv[0] = m;
    mv[1] = rsqrtf(v + 1e-5f);
  }
  __syncthreads();
  mu = mv[0];
  inv_std = mv[1];
}

__global__ __launch_bounds__(256) void sample_ln_kernel(
    const float* __restrict__ field, const float* __restrict__ pos,
    const float* __restrict__ emb, const float* __restrict__ g,
    const float* __restrict__ be, short* __restrict__ enhb)
{
  const size_t row = blockIdx.x;
  const int b = (int)(row >> 11);
  const int t = threadIdx.x;

  const float p = pos[row];
  const float u = fminf(fmaxf(p, 0.0f), 1.0f) * 511.0f;
  int i0 = (int)floorf(u);
  if (i0 > MM - 2) i0 = MM - 2;
  if (i0 < 0) i0 = 0;
  const float w = u - (float)i0;

  const float* f0 = field + ((size_t)b * MM + i0) * DD;
  const int j = t * 2;
  const float2 a0 = *(const float2*)(f0 + j);
  const float2 a1 = *(const float2*)(f0 + DD + j);
  const float2 e = *(const float2*)(emb + row * DD + j);
  const float sx = (1.0f - w) * a0.x + w * a1.x + e.x;
  const float sy = (1.0f - w) * a0.y + w * a1.y + e.y;

  float mu, is;
  ln_stats_512(sx + sy, sx * sx + sy * sy, mu, is);

  const float2 gg = *(const float2*)(g + j);
  const float2 bb2 = *(const float2*)(be + j);
  *(short2*)&enhb[row * DD + j] = make_short2(
      f2b((sx - mu) * is * gg.x + bb2.x),
      f2b((sy - mu) * is * gg.y + bb2.y));
}

__global__ __launch_bounds__(256) void ln2_kernel(
    float* __restrict__ out, const float* __restrict__ g,
    const float* __restrict__ be)
{
  const size_t row = blockIdx.x;
  const int t = threadIdx.x;
  const int j = t * 2;
  const float2 x = *(const float2*)(out + row * DD + j);
  float mu, is;
  ln_stats_512(x.x + x.y, x.x * x.x + x.y * x.y, mu, is);
  const float2 gg = *(const float2*)(g + j);
  const float2 bb2 = *(const float2*)(be + j);
  float2 o;
  o.x = (x.x - mu) * is * gg.x + bb2.x;
  o.y = (x.y - mu) * is * gg.y + bb2.y;
  *(float2*)(out + row * DD + j) = o;
}

// ---------------------------------------------------------------------------

extern "C" void kernel_launch(void* const* d_in, const int* in_sizes, int n_in,
                              void* d_out, int out_size, void* d_ws, size_t ws_size,
                              hipStream_t stream)
{
  const float* emb   = (const float*)d_in[0];
  const float* pos   = (const float*)d_in[1];
  const float* sigma = (const float*)d_in[2];
  const float* alpha = (const float*)d_in[3];
  const float* w_int = (const float*)d_in[4];
  const float* b_int = (const float*)d_in[5];
  const float* diffc = (const float*)d_in[6];
  const float* W1    = (const float*)d_in[7];
  const float* b1    = (const float*)d_in[8];
  const float* W2    = (const float*)d_in[9];
  const float* b2    = (const float*)d_in[10];
  const float* evoc  = (const float*)d_in[11];
  const float* ln1g  = (const float*)d_in[12];
  const float* ln1b  = (const float*)d_in[13];
  const float* Wout  = (const float*)d_in[14];
  const float* bout  = (const float*)d_in[15];
  const float* ln2g  = (const float*)d_in[16];
  const float* ln2b  = (const float*)d_in[17];

  float* out = (float*)d_out;
  char* w = (char*)d_ws;
  // ws map (bytes): f0[0,16.78M) f1[16.78M,33.55M) mixb[33.55M,41.94M)
  //                 hb[41.94M,50.33M) embT[50.33M,83.89M) wT[83.89M,85.98M)
  //                 enhb overlays [16.78M,50.33M) after field ops complete.
  float* f0    = (float*)w;
  float* f1    = (float*)(w + 16777216);
  short* mixb  = (short*)(w + 33554432);
  short* hb    = (short*)(w + 41943040);
  short* enhb  = (short*)(w + 16777216);
  short* embT  = (short*)(w + 50331648);
  short* wT    = (short*)(w + 83886080);
  short* wintT = wT;
  short* w1T   = wT + (size_t)DD * DD;
  short* w2T   = wT + (size_t)2 * DD * DD;
  short* woutT = wT + (size_t)3 * DD * DD;

  const dim3 blk(256);
  const int diff_blocks = BB * MM * DD / 4 / 256;

  wtrans_kernel<<<dim3(16, 16, 4), blk, 0, stream>>>(w_int, W1, W2, Wout, wT);
  embtrans_kernel<<<dim3(64, 16, 16), blk, 0, stream>>>(emb, embT);

  // 1) RBF projection (A computed on the fly) -> f0
  gemm_mfma<64, 1, 4, 0, 0, false, true, false, true>
      <<<dim3(MM / 64, 4, BB), blk, 0, stream>>>(
          nullptr, embT, nullptr, nullptr, f0, nullptr, pos, sigma, NN);

  // 2) head mix -> mixb ; field += mix@w_int + b_int (in place f0)
  mix_kernel<<<dim3(BB * MM), blk, 0, stream>>>(f0, alpha, mixb);
  gemm_mfma<64, 1, 4, 0, 1, true, true, false, false>
      <<<dim3(BB * MM / 64, 4, 1), blk, 0, stream>>>(
          mixb, wintT, b_int, f0, f0, nullptr, nullptr, nullptr, DD);

  // 3) diffusion x3: f0->f1->f0->f1 (last also writes bf16 into mixb slot)
  diffuse_kernel<false><<<dim3(diff_blocks), blk, 0, stream>>>(f0, f1, diffc, nullptr);
  diffuse_kernel<false><<<dim3(diff_blocks), blk, 0, stream>>>(f1, f0, diffc, nullptr);
  diffuse_kernel<true ><<<dim3(diff_blocks), blk, 0, stream>>>(f0, f1, diffc, mixb);

  // 4) MLP: hb = gelu(field@W1+b1) bf16 ; field = hb@W2 + b2 + field (f1)
  gemm_mfma<64, 1, 4, 1, 0, true, false, true, false>
      <<<dim3(BB * MM / 64, 4, 1), blk, 0, stream>>>(
          mixb, w1T, b1, nullptr, nullptr, hb, nullptr, nullptr, DD);
  gemm_mfma<64, 1, 4, 0, 1, true, true, false, false>
      <<<dim3(BB * MM / 64, 4, 1), blk, 0, stream>>>(
          hb, w2T, b2, f1, f1, nullptr, nullptr, nullptr, DD);

  // 5) diffusion x3: f1->f0->f1->f0
  diffuse_kernel<false><<<dim3(diff_blocks), blk, 0, stream>>>(f1, f0, evoc, nullptr);
  diffuse_kernel<false><<<dim3(diff_blocks), blk, 0, stream>>>(f0, f1, evoc, nullptr);
  diffuse_kernel<false><<<dim3(diff_blocks), blk, 0, stream>>>(f1, f0, evoc, nullptr);

  // 6+7a) sample + residual + LN1 -> enhb (bf16; overlays f1/mixb/hb)
  sample_ln_kernel<<<dim3(BB * NN), blk, 0, stream>>>(f0, pos, emb, ln1g, ln1b, enhb);

  // 7b) out = enh@Wout + bout + enh ; LN2 in place
  gemm_mfma<128, 2, 2, 0, 2, true, true, false, false>
      <<<dim3(BB * NN / 128, 4, 1), blk, 0, stream>>>(
          enhb, woutT, bout, enhb, out, nullptr, nullptr, nullptr, DD);
  ln2_kernel<<<dim3(BB * NN), blk, 0, stream>>>(out, ln2g, ln2b);
}

// Round 3
// 368.676 us; speedup vs baseline: 2.5435x; 1.1768x over previous
//
#include <hip/hip_runtime.h>
#include <hip/hip_bf16.h>
#include <math.h>

#define BB 16
#define NN 2048
#define DD 512
#define MM 512

typedef __attribute__((ext_vector_type(8))) short bf16x8;
typedef __attribute__((ext_vector_type(4))) float f32x4;

__device__ __forceinline__ short f2b(float x) {
  union { __hip_bfloat16 h; short s; } u; u.h = __float2bfloat16(x); return u.s;
}
__device__ __forceinline__ float b2f(short s) {
  union { short s2; __hip_bfloat16 h; } u; u.s2 = s; return __bfloat162float(u.h);
}
__device__ __forceinline__ float gelu_f(float x) {
  float x3 = x * x * x;
  return 0.5f * x * (1.0f + tanhf(0.79788456080286536f * (x + 0.044715f * x3)));
}

// ---------------------------------------------------------------------------
// Generic bf16 MFMA GEMM: C[row][col] = act(A@B^T' + bias) + res
// A: [R][K] bf16 row-major; BT: [Ncols][K] bf16 (B transposed, k-contiguous)
// BATCH=true: grid (BB, R/BM, Ncols/BN) — batch in blockIdx.x so each batch's
// working set (Kmat slab + embT slab, ~4MB) lands on one XCD's L2 (id%8).
// mfma_f32_16x16x32_bf16: A/B frag idx=lane&15, k=(lane>>4)*8+0..7;
// C/D frag col=lane&15, row=(lane>>4)*4+reg  [verified m89/m91]
// ---------------------------------------------------------------------------
template<int BM, int BN, int NT, int WR, int WC, int ACT, int RES,
         bool BIAS, bool WB32, bool WB16, bool BATCH>
__global__ __launch_bounds__(NT) void gemm_mfma(
    const short* __restrict__ A, const short* __restrict__ BT,
    const float* __restrict__ bias, const void* __restrict__ res,
    float* __restrict__ C, short* __restrict__ Cb, int K)
{
  constexpr int WAVES = NT / 64;
  constexpr int MF = BM / WR / 16;
  constexpr int NF = BN / WC / 16;
  constexpr int WMT = BM / WR;
  constexpr int WNT = BN / WC;
  constexpr int CHA = BM / 16;   // 1KB chunks in A tile
  constexpr int CHB = BN / 16;

  __shared__ short As[BM * 32];
  __shared__ short Bs[BN * 32];

  const int tid = threadIdx.x;
  const int wid = tid >> 6, lane = tid & 63;
  const int lrow = lane & 15, kg = lane >> 4;
  const int wr = (WR == 1) ? 0 : (wid >> 1);
  const int wc = (WR == 1) ? wid : (wid & 1);

  int r0, c0, z;
  if constexpr (BATCH) {
    z = blockIdx.x; r0 = blockIdx.y * BM; c0 = blockIdx.z * BN;
  } else {
    z = 0; r0 = blockIdx.x * BM; c0 = blockIdx.y * BN;
  }
  const size_t zA  = BATCH ? (size_t)z * MM * K : 0;
  const size_t zBT = BATCH ? (size_t)z * DD * K : 0;
  const size_t zC  = BATCH ? (size_t)z * MM * DD : 0;

  f32x4 acc[MF][NF];
  #pragma unroll
  for (int m = 0; m < MF; ++m)
    #pragma unroll
    for (int n = 0; n < NF; ++n) acc[m][n] = (f32x4){0.f, 0.f, 0.f, 0.f};

  for (int kc = 0; kc < K; kc += 32) {
    // --- B staging (global_load_lds width 16) ---
    #pragma unroll
    for (int i = 0; i < CHB / WAVES; ++i) {
      const int ch = wid * (CHB / WAVES) + i;
      const int col = ch * 16 + (lane >> 2);
      const short* gp = BT + zBT + (size_t)(c0 + col) * K + kc + (lane & 3) * 8;
      __builtin_amdgcn_global_load_lds(
          (const __attribute__((address_space(1))) void*)gp,
          (__attribute__((address_space(3))) void*)&Bs[ch * 512], 16, 0, 0);
    }
    // --- A staging ---
    if constexpr (CHA >= WAVES) {
      #pragma unroll
      for (int i = 0; i < CHA / WAVES; ++i) {
        const int ch = wid * (CHA / WAVES) + i;
        const int row = ch * 16 + (lane >> 2);
        const short* gp = A + zA + (size_t)(r0 + row) * K + kc + (lane & 3) * 8;
        __builtin_amdgcn_global_load_lds(
            (const __attribute__((address_space(1))) void*)gp,
            (__attribute__((address_space(3))) void*)&As[ch * 512], 16, 0, 0);
      }
    } else {
      if (wid < CHA) {
        const int ch = wid;
        const int row = ch * 16 + (lane >> 2);
        const short* gp = A + zA + (size_t)(r0 + row) * K + kc + (lane & 3) * 8;
        __builtin_amdgcn_global_load_lds(
            (const __attribute__((address_space(1))) void*)gp,
            (__attribute__((address_space(3))) void*)&As[ch * 512], 16, 0, 0);
      }
    }
    __syncthreads();

    bf16x8 af[MF], bfv[NF];
    #pragma unroll
    for (int m = 0; m < MF; ++m)
      af[m] = *(const bf16x8*)&As[(wr * WMT + m * 16 + lrow) * 32 + kg * 8];
    #pragma unroll
    for (int n = 0; n < NF; ++n)
      bfv[n] = *(const bf16x8*)&Bs[(wc * WNT + n * 16 + lrow) * 32 + kg * 8];
    #pragma unroll
    for (int m = 0; m < MF; ++m)
      #pragma unroll
      for (int n = 0; n < NF; ++n)
        acc[m][n] = __builtin_amdgcn_mfma_f32_16x16x32_bf16(af[m], bfv[n], acc[m][n], 0, 0, 0);
    __syncthreads();
  }

  #pragma unroll
  for (int m = 0; m < MF; ++m) {
    #pragma unroll
    for (int n = 0; n < NF; ++n) {
      const int col = c0 + wc * WNT + n * 16 + lrow;
      const int row0 = r0 + wr * WMT + m * 16 + kg * 4;
      float bi = 0.0f;
      if constexpr (BIAS) bi = bias[col];
      #pragma unroll
      for (int r = 0; r < 4; ++r) {
        float x = acc[m][n][r] + bi;
        if constexpr (ACT == 1) x = gelu_f(x);
        const size_t off = zC + (size_t)(row0 + r) * DD + col;
        if constexpr (RES == 1) x += ((const float*)res)[off];
        if constexpr (RES == 2) x += b2f(((const short*)res)[off]);
        if constexpr (WB32) C[off] = x;
        if constexpr (WB16) Cb[off] = f2b(x);
      }
    }
  }
}

// ---------------------------------------------------------------------------
// Kmat precompute: Kmat[b][m][n] = exp(-(g_m - p_bn)^2 / (2 sigma^2)) in bf16
// 8 n-values per thread; coalesced 16B stores. grid 8192 x 256.
// ---------------------------------------------------------------------------
__global__ __launch_bounds__(256) void kmat_kernel(
    const float* __restrict__ pos, const float* __restrict__ sigp,
    short* __restrict__ Kmat)
{
  const int gid = blockIdx.x * 256 + threadIdx.x;
  const int n8 = gid & 255;          // NN/8 = 256
  const int m  = (gid >> 8) & (MM - 1);
  const int b  = gid >> 17;
  const float s = sigp[0];
  const float inv2s2 = 1.0f / (2.0f * s * s);
  const float g = (float)m * (1.0f / 511.0f);
  const float* pp = pos + (size_t)b * NN + n8 * 8;
  const float4 p0 = *(const float4*)pp;
  const float4 p1 = *(const float4*)(pp + 4);
  const float pv[8] = {p0.x, p0.y, p0.z, p0.w, p1.x, p1.y, p1.z, p1.w};
  bf16x8 o;
  #pragma unroll
  for (int j = 0; j < 8; ++j) {
    const float d = g - pv[j];
    o[j] = f2b(__expf(-(d * d) * inv2s2));
  }
  *(bf16x8*)&Kmat[((size_t)b * MM + m) * NN + n8 * 8] = o;
}

// ---------------------------------------------------------------------------
// Weight transpose fp32->bf16: WT[c][k] = W[k][c]
// ---------------------------------------------------------------------------
__global__ __launch_bounds__(256) void wtrans_kernel(
    const float* __restrict__ w0, const float* __restrict__ w1,
    const float* __restrict__ w2, const float* __restrict__ w3,
    short* __restrict__ outW)
{
  __shared__ float tle[32][33];
  const int z = blockIdx.z;
  const float* W = (z == 0) ? w0 : (z == 1) ? w1 : (z == 2) ? w2 : w3;
  short* WT = outW + (size_t)z * DD * DD;
  const int bx = blockIdx.x * 32;
  const int by = blockIdx.y * 32;
  const int t = threadIdx.x;
  const int r = t >> 3, c4 = (t & 7) * 4;
  const float4 v = *(const float4*)(W + (size_t)(bx + r) * DD + by + c4);
  tle[r][c4 + 0] = v.x; tle[r][c4 + 1] = v.y; tle[r][c4 + 2] = v.z; tle[r][c4 + 3] = v.w;
  __syncthreads();
  const short4 o = make_short4(f2b(tle[c4 + 0][r]), f2b(tle[c4 + 1][r]),
                               f2b(tle[c4 + 2][r]), f2b(tle[c4 + 3][r]));
  *(short4*)(WT + (size_t)(by + r) * DD + bx + c4) = o;
}

// emb [b][n][d] fp32 -> embT [b][d][n] bf16
__global__ __launch_bounds__(256) void embtrans_kernel(
    const float* __restrict__ emb, short* __restrict__ embT)
{
  __shared__ float tle[32][33];
  const int z = blockIdx.z;
  const int bx = blockIdx.x * 32;  // n tile
  const int by = blockIdx.y * 32;  // d tile
  const int t = threadIdx.x;
  const int r = t >> 3, c4 = (t & 7) * 4;
  const float4 v = *(const float4*)(emb + ((size_t)z * NN + bx + r) * DD + by + c4);
  tle[r][c4 + 0] = v.x; tle[r][c4 + 1] = v.y; tle[r][c4 + 2] = v.z; tle[r][c4 + 3] = v.w;
  __syncthreads();
  const short4 o = make_short4(f2b(tle[c4 + 0][r]), f2b(tle[c4 + 1][r]),
                               f2b(tle[c4 + 2][r]), f2b(tle[c4 + 3][r]));
  *(short4*)(embT + ((size_t)z * DD + by + r) * NN + bx + c4) = o;
}

// ---------------------------------------------------------------------------
// head mix -> bf16
// ---------------------------------------------------------------------------
__global__ __launch_bounds__(256) void mix_kernel(
    const float* __restrict__ field, const float* __restrict__ alpha,
    short* __restrict__ mixout)
{
  __shared__ float row[DD];
  __shared__ float al[64];
  const size_t r = blockIdx.x;
  const int t = threadIdx.x;
  const float* fr = field + r * DD;
  *(float2*)&row[t * 2] = *(const float2*)&fr[t * 2];
  if (t < 64) al[t] = alpha[t];
  __syncthreads();
  const int j = t * 2;
  const int h = j >> 6;
  const int jj = j & 63;
  float s0 = 0.0f, s1 = 0.0f;
  #pragma unroll
  for (int k = 0; k < 8; ++k) {
    const float a = al[h * 8 + k];
    const float2 v = *(const float2*)&row[k * 64 + jj];
    s0 += a * v.x;
    s1 += a * v.y;
  }
  *(short2*)&mixout[r * DD + j] = make_short2(f2b(s0), f2b(s1));
}

// ---------------------------------------------------------------------------
// Fused 3-step diffusion chain. Each thread: 7-row clamped float4 window,
// simulate 3 explicit-Euler steps in registers. Clamped loads reproduce the
// Neumann edge-pad semantics exactly (duplication is preserved step to step).
// Neighbor rows served by L1/L2 (row = 2KB, halo +-3 rows).
// ---------------------------------------------------------------------------
__device__ __forceinline__ float4 dstep(float4 fm, float4 f, float4 fp, float4 a) {
  float4 o;
  o.x = f.x + a.x * (fm.x - 2.0f * f.x + fp.x);
  o.y = f.y + a.y * (fm.y - 2.0f * f.y + fp.y);
  o.z = f.z + a.z * (fm.z - 2.0f * f.z + fp.z);
  o.w = f.w + a.w * (fm.w - 2.0f * f.w + fp.w);
  return o;
}

template<bool WB16>
__global__ __launch_bounds__(256) void diffuse3_kernel(
    const float* __restrict__ in, float* __restrict__ out,
    const float* __restrict__ coef, short* __restrict__ bfout)
{
  const size_t base = ((size_t)blockIdx.x * 256 + threadIdx.x) * 4;
  const int d = (int)(base & (DD - 1));
  const int m = (int)((base >> 9) & (MM - 1));
  const size_t rowbase = base - (size_t)m * DD;

  float4 u[7];
  #pragma unroll
  for (int o = 0; o < 7; ++o) {
    int mm = m + o - 3;
    mm = mm < 0 ? 0 : (mm > MM - 1 ? MM - 1 : mm);
    u[o] = *(const float4*)(in + rowbase + (size_t)mm * DD);
  }
  const float4 c = *(const float4*)(coef + d);
  float4 a;
  a.x = 0.01f * c.x; a.y = 0.01f * c.y; a.z = 0.01f * c.z; a.w = 0.01f * c.w;

  float4 v[5];
  #pragma unroll
  for (int o = 0; o < 5; ++o) v[o] = dstep(u[o], u[o + 1], u[o + 2], a);
  float4 w2[3];
  #pragma unroll
  for (int o = 0; o < 3; ++o) w2[o] = dstep(v[o], v[o + 1], v[o + 2], a);
  const float4 r = dstep(w2[0], w2[1], w2[2], a);

  *(float4*)(out + base) = r;
  if constexpr (WB16) {
    *(short4*)(bfout + base) = make_short4(f2b(r.x), f2b(r.y), f2b(r.z), f2b(r.w));
  }
}

// ---------------------------------------------------------------------------
// LN helpers / sampling
// ---------------------------------------------------------------------------
__device__ __forceinline__ void ln_stats_512(float sum, float sq, float& mu, float& inv_std) {
  #pragma unroll
  for (int off = 32; off >= 1; off >>= 1) {
    sum += __shfl_down(sum, off);
    sq  += __shfl_down(sq,  off);
  }
  __shared__ float red[8];
  __shared__ float mv[2];
  const int lane = threadIdx.x & 63;
  const int wid = threadIdx.x >> 6;
  if (lane == 0) { red[wid] = sum; red[4 + wid] = sq; }
  __syncthreads();
  if (threadIdx.x == 0) {
    float ts = red[0] + red[1] + red[2] + red[3];
    float tq = red[4] + red[5] + red[6] + red[7];
    float m = ts * (1.0f / 512.0f);
    float v = tq * (1.0f / 512.0f) - m * m;
    mv[0] = m;
    mv[1] = rsqrtf(v + 1e-5f);
  }
  __syncthreads();
  mu = mv[0];
  inv_std = mv[1];
}

__global__ __launch_bounds__(256) void sample_ln_kernel(
    const float* __restrict__ field, const float* __restrict__ pos,
    const float* __restrict__ emb, const float* __restrict__ g,
    const float* __restrict__ be, short* __restrict__ enhb)
{
  const size_t row = blockIdx.x;
  const int b = (int)(row >> 11);
  const int t = threadIdx.x;

  const float p = pos[row];
  const float u = fminf(fmaxf(p, 0.0f), 1.0f) * 511.0f;
  int i0 = (int)floorf(u);
  if (i0 > MM - 2) i0 = MM - 2;
  if (i0 < 0) i0 = 0;
  const float w = u - (float)i0;

  const float* f0 = field + ((size_t)b * MM + i0) * DD;
  const int j = t * 2;
  const float2 a0 = *(const float2*)(f0 + j);
  const float2 a1 = *(const float2*)(f0 + DD + j);
  const float2 e = *(const float2*)(emb + row * DD + j);
  const float sx = (1.0f - w) * a0.x + w * a1.x + e.x;
  const float sy = (1.0f - w) * a0.y + w * a1.y + e.y;

  float mu, is;
  ln_stats_512(sx + sy, sx * sx + sy * sy, mu, is);

  const float2 gg = *(const float2*)(g + j);
  const float2 bb2 = *(const float2*)(be + j);
  *(short2*)&enhb[row * DD + j] = make_short2(
      f2b((sx - mu) * is * gg.x + bb2.x),
      f2b((sy - mu) * is * gg.y + bb2.y));
}

__global__ __launch_bounds__(256) void ln2_kernel(
    float* __restrict__ out, const float* __restrict__ g,
    const float* __restrict__ be)
{
  const size_t row = blockIdx.x;
  const int t = threadIdx.x;
  const int j = t * 2;
  const float2 x = *(const float2*)(out + row * DD + j);
  float mu, is;
  ln_stats_512(x.x + x.y, x.x * x.x + x.y * x.y, mu, is);
  const float2 gg = *(const float2*)(g + j);
  const float2 bb2 = *(const float2*)(be + j);
  float2 o;
  o.x = (x.x - mu) * is * gg.x + bb2.x;
  o.y = (x.y - mu) * is * gg.y + bb2.y;
  *(float2*)(out + row * DD + j) = o;
}

// ---------------------------------------------------------------------------

extern "C" void kernel_launch(void* const* d_in, const int* in_sizes, int n_in,
                              void* d_out, int out_size, void* d_ws, size_t ws_size,
                              hipStream_t stream)
{
  const float* emb   = (const float*)d_in[0];
  const float* pos   = (const float*)d_in[1];
  const float* sigma = (const float*)d_in[2];
  const float* alpha = (const float*)d_in[3];
  const float* w_int = (const float*)d_in[4];
  const float* b_int = (const float*)d_in[5];
  const float* diffc = (const float*)d_in[6];
  const float* W1    = (const float*)d_in[7];
  const float* b1    = (const float*)d_in[8];
  const float* W2    = (const float*)d_in[9];
  const float* b2    = (const float*)d_in[10];
  const float* evoc  = (const float*)d_in[11];
  const float* ln1g  = (const float*)d_in[12];
  const float* ln1b  = (const float*)d_in[13];
  const float* Wout  = (const float*)d_in[14];
  const float* bout  = (const float*)d_in[15];
  const float* ln2g  = (const float*)d_in[16];
  const float* ln2b  = (const float*)d_in[17];

  float* out = (float*)d_out;
  char* w = (char*)d_ws;
  // ws map (bytes), total 86.0 MB (<= 100.7 MB proven in round 0):
  //   f0   [0,        16.78M)                       fp32 field ping
  //   Kmat [16.78M,   50.33M)  bf16 [B][M][N]       dead after RBF GEMM
  //   f1   [16.78M,   33.55M)  overlays Kmat lo     first write: diffuse3 #1
  //   mixb [33.55M,   41.94M)  overlays Kmat mid    first write: mix_kernel
  //   hb   [41.94M,   50.33M)  overlays Kmat hi     first write: W1 GEMM
  //   embT [50.33M,   83.89M)  bf16 [B][D][N]       dead after RBF GEMM
  //   enhb [50.33M,   83.89M)  overlays embT        first write: sample_ln
  //   wT   [83.89M,   85.98M)  4x 512x512 bf16
  float* f0    = (float*)w;
  short* Kmat  = (short*)(w + 16777216);
  float* f1    = (float*)(w + 16777216);
  short* mixb  = (short*)(w + 33554432);
  short* hb    = (short*)(w + 41943040);
  short* embT  = (short*)(w + 50331648);
  short* enhb  = (short*)(w + 50331648);
  short* wT    = (short*)(w + 83886080);
  short* wintT = wT;
  short* w1T   = wT + (size_t)DD * DD;
  short* w2T   = wT + (size_t)2 * DD * DD;
  short* woutT = wT + (size_t)3 * DD * DD;

  const dim3 blk(256);
  const int diff_blocks = BB * MM * DD / 4 / 256;  // 4096

  // 0) weight + emb transposes, Kmat precompute
  wtrans_kernel<<<dim3(16, 16, 4), blk, 0, stream>>>(w_int, W1, W2, Wout, wT);
  embtrans_kernel<<<dim3(64, 16, 16), blk, 0, stream>>>(emb, embT);
  kmat_kernel<<<dim3(BB * MM * NN / 8 / 256), blk, 0, stream>>>(pos, sigma, Kmat);

  // 1) RBF projection: pure bf16 GEMM, batch-major grid for XCD L2 locality
  gemm_mfma<64, 128, 256, 1, 4, 0, 0, false, true, false, true>
      <<<dim3(BB, MM / 64, DD / 128), blk, 0, stream>>>(
          Kmat, embT, nullptr, nullptr, f0, nullptr, NN);

  // 2) head mix -> mixb ; field += mix@w_int + b_int (in place f0)
  mix_kernel<<<dim3(BB * MM), blk, 0, stream>>>(f0, alpha, mixb);
  gemm_mfma<64, 128, 256, 1, 4, 0, 1, true, true, false, false>
      <<<dim3(BB * MM / 64, DD / 128), blk, 0, stream>>>(
          mixb, wintT, b_int, f0, f0, nullptr, DD);

  // 3) fused diffusion chain 1: f0 -> f1 (+ bf16 copy into mixb for MLP A)
  diffuse3_kernel<true><<<dim3(diff_blocks), blk, 0, stream>>>(f0, f1, diffc, mixb);

  // 4) MLP: hb = gelu(field@W1+b1) bf16 ; field = hb@W2 + b2 + field (f1)
  gemm_mfma<64, 128, 256, 1, 4, 1, 0, true, false, true, false>
      <<<dim3(BB * MM / 64, DD / 128), blk, 0, stream>>>(
          mixb, w1T, b1, nullptr, nullptr, hb, DD);
  gemm_mfma<64, 128, 256, 1, 4, 0, 1, true, true, false, false>
      <<<dim3(BB * MM / 64, DD / 128), blk, 0, stream>>>(
          hb, w2T, b2, f1, f1, nullptr, DD);

  // 5) fused diffusion chain 2: f1 -> f0
  diffuse3_kernel<false><<<dim3(diff_blocks), blk, 0, stream>>>(f1, f0, evoc, nullptr);

  // 6+7a) sample + residual + LN1 -> enhb (bf16)
  sample_ln_kernel<<<dim3(BB * NN), blk, 0, stream>>>(f0, pos, emb, ln1g, ln1b, enhb);

  // 7b) out = enh@Wout + bout + enh : BN=512 so Wout stays L2-resident and
  //     A (enh) is fetched exactly once; 512-thread blocks, grid 512.
  gemm_mfma<64, 512, 512, 1, 8, 0, 2, true, true, false, false>
      <<<dim3(BB * NN / 64, 1), dim3(512), 0, stream>>>(
          enhb, woutT, bout, enhb, out, nullptr, DD);
  ln2_kernel<<<dim3(BB * NN), blk, 0, stream>>>(out, ln2g, ln2b);
}

// Round 5
// 347.939 us; speedup vs baseline: 2.6951x; 1.0596x over previous
//
#include <hip/hip_runtime.h>
#include <hip/hip_bf16.h>
#include <math.h>

#define BB 16
#define NN 2048
#define DD 512
#define MM 512

typedef __attribute__((ext_vector_type(8))) short bf16x8;
typedef __attribute__((ext_vector_type(4))) float f32x4;

__device__ __forceinline__ short f2b(float x) {
  union { __hip_bfloat16 h; short s; } u; u.h = __float2bfloat16(x); return u.s;
}
__device__ __forceinline__ float b2f(short s) {
  union { short s2; __hip_bfloat16 h; } u; u.s2 = s; return __bfloat162float(u.h);
}
__device__ __forceinline__ float gelu_f(float x) {
  float x3 = x * x * x;
  return 0.5f * x * (1.0f + tanhf(0.79788456080286536f * (x + 0.044715f * x3)));
}

// ---------------------------------------------------------------------------
// Generic bf16 MFMA GEMM, 2-phase double-buffered (T3 minimum recipe):
//   prologue: STAGE(buf0, k=0); barrier;
//   loop:     STAGE(buf^1, k+32); ds_read buf; MFMA; barrier; buf^=1;
// One barrier per K-step; next-tile loads fly under current-tile compute.
// A: [R][K] bf16 row-major; BT: [Ncols][K] bf16 (k-contiguous).
// mfma_f32_16x16x32_bf16: A/B frag idx=lane&15, k=(lane>>4)*8+0..7;
// C/D frag col=lane&15, row=(lane>>4)*4+reg  [verified m89/m91]
// ---------------------------------------------------------------------------
template<int BM, int BN, int NT, int WR, int WC, int ACT, int RES,
         bool BIAS, bool WB32, bool WB16, bool BATCH>
__global__ __launch_bounds__(NT) void gemm_mfma(
    const short* __restrict__ A, const short* __restrict__ BT,
    const float* __restrict__ bias, const void* __restrict__ res,
    float* __restrict__ C, short* __restrict__ Cb, int K)
{
  constexpr int WAVES = NT / 64;
  constexpr int MF = BM / WR / 16;
  constexpr int NF = BN / WC / 16;
  constexpr int WMT = BM / WR;
  constexpr int WNT = BN / WC;
  constexpr int CHA = BM / 16;   // 1KB chunks in one A k-tile
  constexpr int CHB = BN / 16;

  __shared__ short As[2][BM * 32];
  __shared__ short Bs[2][BN * 32];

  const int tid = threadIdx.x;
  const int wid = tid >> 6, lane = tid & 63;
  const int lrow = lane & 15, kg = lane >> 4;
  const int wr = (WR == 1) ? 0 : (wid >> 1);
  const int wc = (WR == 1) ? wid : (wid & 1);

  int r0, c0, z;
  if constexpr (BATCH) {
    z = blockIdx.x; r0 = blockIdx.y * BM; c0 = blockIdx.z * BN;
  } else {
    z = 0; r0 = blockIdx.x * BM; c0 = blockIdx.y * BN;
  }
  const size_t zA  = BATCH ? (size_t)z * MM * K : 0;
  const size_t zBT = BATCH ? (size_t)z * DD * K : 0;
  const size_t zC  = BATCH ? (size_t)z * MM * DD : 0;

  auto stage = [&](int bf, int kc) {
    #pragma unroll
    for (int i = 0; i < CHB / WAVES; ++i) {
      const int ch = wid * (CHB / WAVES) + i;
      const int col = ch * 16 + (lane >> 2);
      const short* gp = BT + zBT + (size_t)(c0 + col) * K + kc + (lane & 3) * 8;
      __builtin_amdgcn_global_load_lds(
          (const __attribute__((address_space(1))) void*)gp,
          (__attribute__((address_space(3))) void*)&Bs[bf][ch * 512], 16, 0, 0);
    }
    if constexpr (CHA >= WAVES) {
      #pragma unroll
      for (int i = 0; i < CHA / WAVES; ++i) {
        const int ch = wid * (CHA / WAVES) + i;
        const int row = ch * 16 + (lane >> 2);
        const short* gp = A + zA + (size_t)(r0 + row) * K + kc + (lane & 3) * 8;
        __builtin_amdgcn_global_load_lds(
            (const __attribute__((address_space(1))) void*)gp,
            (__attribute__((address_space(3))) void*)&As[bf][ch * 512], 16, 0, 0);
      }
    } else {
      if (wid < CHA) {
        const int row = wid * 16 + (lane >> 2);
        const short* gp = A + zA + (size_t)(r0 + row) * K + kc + (lane & 3) * 8;
        __builtin_amdgcn_global_load_lds(
            (const __attribute__((address_space(1))) void*)gp,
            (__attribute__((address_space(3))) void*)&As[bf][wid * 512], 16, 0, 0);
      }
    }
  };

  f32x4 acc[MF][NF];
  #pragma unroll
  for (int m = 0; m < MF; ++m)
    #pragma unroll
    for (int n = 0; n < NF; ++n) acc[m][n] = (f32x4){0.f, 0.f, 0.f, 0.f};

  stage(0, 0);
  __syncthreads();

  int buf = 0;
  for (int kc = 0; kc < K; kc += 32) {
    if (kc + 32 < K) stage(buf ^ 1, kc + 32);

    bf16x8 af[MF], bfv[NF];
    #pragma unroll
    for (int m = 0; m < MF; ++m)
      af[m] = *(const bf16x8*)&As[buf][(wr * WMT + m * 16 + lrow) * 32 + kg * 8];
    #pragma unroll
    for (int n = 0; n < NF; ++n)
      bfv[n] = *(const bf16x8*)&Bs[buf][(wc * WNT + n * 16 + lrow) * 32 + kg * 8];
    #pragma unroll
    for (int m = 0; m < MF; ++m)
      #pragma unroll
      for (int n = 0; n < NF; ++n)
        acc[m][n] = __builtin_amdgcn_mfma_f32_16x16x32_bf16(af[m], bfv[n], acc[m][n], 0, 0, 0);

    __syncthreads();   // drains next-tile vmcnt + protects buf reuse
    buf ^= 1;
  }

  #pragma unroll
  for (int m = 0; m < MF; ++m) {
    #pragma unroll
    for (int n = 0; n < NF; ++n) {
      const int col = c0 + wc * WNT + n * 16 + lrow;
      const int row0 = r0 + wr * WMT + m * 16 + kg * 4;
      float bi = 0.0f;
      if constexpr (BIAS) bi = bias[col];
      #pragma unroll
      for (int r = 0; r < 4; ++r) {
        float x = acc[m][n][r] + bi;
        if constexpr (ACT == 1) x = gelu_f(x);
        const size_t off = zC + (size_t)(row0 + r) * DD + col;
        if constexpr (RES == 1) x += ((const float*)res)[off];
        if constexpr (RES == 2) x += b2f(((const short*)res)[off]);
        if constexpr (WB32) C[off] = x;
        if constexpr (WB16) Cb[off] = f2b(x);
      }
    }
  }
}

// ---------------------------------------------------------------------------
// Output GEMM fused with LN2. BN=512 => each block owns complete rows, so
// LayerNorm row-stats reduce inside the block. Residual +enh is folded into
// the weight (woutT has +I on the diagonal): out_pre = enh @ (Wout+I) + bout,
// then LN(out_pre) -> d_out. 64 rows/block, 512 threads (8 waves), K=512.
// ---------------------------------------------------------------------------
__global__ __launch_bounds__(512) void gemm_out_ln(
    const short* __restrict__ A, const short* __restrict__ BT,
    const float* __restrict__ bias, const float* __restrict__ g,
    const float* __restrict__ be, float* __restrict__ out)
{
  constexpr int BM = 64, BN = 512, K = 512;
  constexpr int WAVES = 8, CHB = BN / 16, CHA = BM / 16;

  __shared__ short As[2][BM * 32];
  __shared__ short Bs[2][BN * 32];
  __shared__ float redS[8][64], redQ[8][64];
  __shared__ float lnMu[64], lnIs[64];

  const int tid = threadIdx.x;
  const int wid = tid >> 6, lane = tid & 63;
  const int lrow = lane & 15, kg = lane >> 4;
  const int wc = wid;                 // 8 waves across 512 cols (64 each)
  const int r0 = blockIdx.x * BM;

  auto stage = [&](int bf, int kc) {
    #pragma unroll
    for (int i = 0; i < CHB / WAVES; ++i) {
      const int ch = wid * (CHB / WAVES) + i;
      const int col = ch * 16 + (lane >> 2);
      const short* gp = BT + (size_t)col * K + kc + (lane & 3) * 8;
      __builtin_amdgcn_global_load_lds(
          (const __attribute__((address_space(1))) void*)gp,
          (__attribute__((address_space(3))) void*)&Bs[bf][ch * 512], 16, 0, 0);
    }
    if (wid < CHA) {
      const int row = wid * 16 + (lane >> 2);
      const short* gp = A + (size_t)(r0 + row) * K + kc + (lane & 3) * 8;
      __builtin_amdgcn_global_load_lds(
          (const __attribute__((address_space(1))) void*)gp,
          (__attribute__((address_space(3))) void*)&As[bf][wid * 512], 16, 0, 0);
    }
  };

  f32x4 acc[4][4];
  #pragma unroll
  for (int m = 0; m < 4; ++m)
    #pragma unroll
    for (int n = 0; n < 4; ++n) acc[m][n] = (f32x4){0.f, 0.f, 0.f, 0.f};

  stage(0, 0);
  __syncthreads();
  int buf = 0;
  for (int kc = 0; kc < K; kc += 32) {
    if (kc + 32 < K) stage(buf ^ 1, kc + 32);
    bf16x8 af[4], bfv[4];
    #pragma unroll
    for (int m = 0; m < 4; ++m)
      af[m] = *(const bf16x8*)&As[buf][(m * 16 + lrow) * 32 + kg * 8];
    #pragma unroll
    for (int n = 0; n < 4; ++n)
      bfv[n] = *(const bf16x8*)&Bs[buf][(wc * 64 + n * 16 + lrow) * 32 + kg * 8];
    #pragma unroll
    for (int m = 0; m < 4; ++m)
      #pragma unroll
      for (int n = 0; n < 4; ++n)
        acc[m][n] = __builtin_amdgcn_mfma_f32_16x16x32_bf16(af[m], bfv[n], acc[m][n], 0, 0, 0);
    __syncthreads();
    buf ^= 1;
  }

  // epilogue: x = acc + bout[col]; per-row LN stats
  #pragma unroll
  for (int m = 0; m < 4; ++m) {
    #pragma unroll
    for (int n = 0; n < 4; ++n) {
      const float bi = bias[wc * 64 + n * 16 + lrow];
      #pragma unroll
      for (int r = 0; r < 4; ++r) acc[m][n][r] += bi;
    }
  }
  #pragma unroll
  for (int m = 0; m < 4; ++m) {
    #pragma unroll
    for (int r = 0; r < 4; ++r) {
      float ps = acc[m][0][r] + acc[m][1][r] + acc[m][2][r] + acc[m][3][r];
      float pq = acc[m][0][r] * acc[m][0][r] + acc[m][1][r] * acc[m][1][r] +
                 acc[m][2][r] * acc[m][2][r] + acc[m][3][r] * acc[m][3][r];
      #pragma unroll
      for (int off = 8; off >= 1; off >>= 1) {
        ps += __shfl_xor(ps, off);
        pq += __shfl_xor(pq, off);
      }
      if (lrow == 0) {
        redS[wid][m * 16 + kg * 4 + r] = ps;
        redQ[wid][m * 16 + kg * 4 + r] = pq;
      }
    }
  }
  __syncthreads();
  if (tid < 64) {
    float s = 0.f, q = 0.f;
    #pragma unroll
    for (int w = 0; w < 8; ++w) { s += redS[w][tid]; q += redQ[w][tid]; }
    const float mu = s * (1.0f / 512.0f);
    const float var = q * (1.0f / 512.0f) - mu * mu;
    lnMu[tid] = mu;
    lnIs[tid] = rsqrtf(var + 1e-5f);
  }
  __syncthreads();
  #pragma unroll
  for (int m = 0; m < 4; ++m) {
    #pragma unroll
    for (int n = 0; n < 4; ++n) {
      const int col = wc * 64 + n * 16 + lrow;
      const float gc = g[col], bc = be[col];
      #pragma unroll
      for (int r = 0; r < 4; ++r) {
        const int row = m * 16 + kg * 4 + r;
        out[(size_t)(r0 + row) * DD + col] =
            (acc[m][n][r] - lnMu[row]) * lnIs[row] * gc + bc;
      }
    }
  }
}

// ---------------------------------------------------------------------------
// Kmat precompute: Kmat[b][m][n] = exp(-(g_m - p_bn)^2 / (2 sigma^2)) bf16
// ---------------------------------------------------------------------------
__global__ __launch_bounds__(256) void kmat_kernel(
    const float* __restrict__ pos, const float* __restrict__ sigp,
    short* __restrict__ Kmat)
{
  const int gid = blockIdx.x * 256 + threadIdx.x;
  const int n8 = gid & 255;
  const int m  = (gid >> 8) & (MM - 1);
  const int b  = gid >> 17;
  const float s = sigp[0];
  const float inv2s2 = 1.0f / (2.0f * s * s);
  const float g = (float)m * (1.0f / 511.0f);
  const float* pp = pos + (size_t)b * NN + n8 * 8;
  const float4 p0 = *(const float4*)pp;
  const float4 p1 = *(const float4*)(pp + 4);
  const float pv[8] = {p0.x, p0.y, p0.z, p0.w, p1.x, p1.y, p1.z, p1.w};
  bf16x8 o;
  #pragma unroll
  for (int j = 0; j < 8; ++j) {
    const float d = g - pv[j];
    o[j] = f2b(__expf(-(d * d) * inv2s2));
  }
  *(bf16x8*)&Kmat[((size_t)b * MM + m) * NN + n8 * 8] = o;
}

// ---------------------------------------------------------------------------
// Weight transpose fp32->bf16: WT[c][k] = W[k][c]; z==3 (Wout) adds +I so the
// output GEMM's +enh residual is folded into the matmul.
// ---------------------------------------------------------------------------
__global__ __launch_bounds__(256) void wtrans_kernel(
    const float* __restrict__ w0, const float* __restrict__ w1,
    const float* __restrict__ w2, const float* __restrict__ w3,
    short* __restrict__ outW)
{
  __shared__ float tle[32][33];
  const int z = blockIdx.z;
  const float* W = (z == 0) ? w0 : (z == 1) ? w1 : (z == 2) ? w2 : w3;
  short* WT = outW + (size_t)z * DD * DD;
  const int bx = blockIdx.x * 32;   // k tile
  const int by = blockIdx.y * 32;   // c tile
  const int t = threadIdx.x;
  const int r = t >> 3, c4 = (t & 7) * 4;
  const float4 v = *(const float4*)(W + (size_t)(bx + r) * DD + by + c4);
  tle[r][c4 + 0] = v.x; tle[r][c4 + 1] = v.y; tle[r][c4 + 2] = v.z; tle[r][c4 + 3] = v.w;
  __syncthreads();
  short4 o;
  #pragma unroll
  for (int j = 0; j < 4; ++j) {
    float val = tle[c4 + j][r];
    if (z == 3 && (bx + c4 + j) == (by + r)) val += 1.0f;
    ((short*)&o)[j] = f2b(val);
  }
  *(short4*)(WT + (size_t)(by + r) * DD + bx + c4) = o;
}

// emb [b][n][d] fp32 -> embT [b][d][n] bf16
__global__ __launch_bounds__(256) void embtrans_kernel(
    const float* __restrict__ emb, short* __restrict__ embT)
{
  __shared__ float tle[32][33];
  const int z = blockIdx.z;
  const int bx = blockIdx.x * 32;  // n tile
  const int by = blockIdx.y * 32;  // d tile
  const int t = threadIdx.x;
  const int r = t >> 3, c4 = (t & 7) * 4;
  const float4 v = *(const float4*)(emb + ((size_t)z * NN + bx + r) * DD + by + c4);
  tle[r][c4 + 0] = v.x; tle[r][c4 + 1] = v.y; tle[r][c4 + 2] = v.z; tle[r][c4 + 3] = v.w;
  __syncthreads();
  const short4 o = make_short4(f2b(tle[c4 + 0][r]), f2b(tle[c4 + 1][r]),
                               f2b(tle[c4 + 2][r]), f2b(tle[c4 + 3][r]));
  *(short4*)(embT + ((size_t)z * DD + by + r) * NN + bx + c4) = o;
}

// ---------------------------------------------------------------------------
// head mix -> bf16
// ---------------------------------------------------------------------------
__global__ __launch_bounds__(256) void mix_kernel(
    const float* __restrict__ field, const float* __restrict__ alpha,
    short* __restrict__ mixout)
{
  __shared__ float row[DD];
  __shared__ float al[64];
  const size_t r = blockIdx.x;
  const int t = threadIdx.x;
  const float* fr = field + r * DD;
  *(float2*)&row[t * 2] = *(const float2*)&fr[t * 2];
  if (t < 64) al[t] = alpha[t];
  __syncthreads();
  const int j = t * 2;
  const int h = j >> 6;
  const int jj = j & 63;
  float s0 = 0.0f, s1 = 0.0f;
  #pragma unroll
  for (int k = 0; k < 8; ++k) {
    const float a = al[h * 8 + k];
    const float2 v = *(const float2*)&row[k * 64 + jj];
    s0 += a * v.x;
    s1 += a * v.y;
  }
  *(short2*)&mixout[r * DD + j] = make_short2(f2b(s0), f2b(s1));
}

// ---------------------------------------------------------------------------
// Fused 3-step diffusion (7-row clamped window, 3 Euler steps in registers)
// ---------------------------------------------------------------------------
__device__ __forceinline__ float4 dstep(float4 fm, float4 f, float4 fp, float4 a) {
  float4 o;
  o.x = f.x + a.x * (fm.x - 2.0f * f.x + fp.x);
  o.y = f.y + a.y * (fm.y - 2.0f * f.y + fp.y);
  o.z = f.z + a.z * (fm.z - 2.0f * f.z + fp.z);
  o.w = f.w + a.w * (fm.w - 2.0f * f.w + fp.w);
  return o;
}

template<bool WB16>
__global__ __launch_bounds__(256) void diffuse3_kernel(
    const float* __restrict__ in, float* __restrict__ out,
    const float* __restrict__ coef, short* __restrict__ bfout)
{
  const size_t base = ((size_t)blockIdx.x * 256 + threadIdx.x) * 4;
  const int d = (int)(base & (DD - 1));
  const int m = (int)((base >> 9) & (MM - 1));
  const size_t rowbase = base - (size_t)m * DD;

  float4 u[7];
  #pragma unroll
  for (int o = 0; o < 7; ++o) {
    int mm = m + o - 3;
    mm = mm < 0 ? 0 : (mm > MM - 1 ? MM - 1 : mm);
    u[o] = *(const float4*)(in + rowbase + (size_t)mm * DD);
  }
  const float4 c = *(const float4*)(coef + d);
  float4 a;
  a.x = 0.01f * c.x; a.y = 0.01f * c.y; a.z = 0.01f * c.z; a.w = 0.01f * c.w;

  float4 v[5];
  #pragma unroll
  for (int o = 0; o < 5; ++o) v[o] = dstep(u[o], u[o + 1], u[o + 2], a);
  float4 w2[3];
  #pragma unroll
  for (int o = 0; o < 3; ++o) w2[o] = dstep(v[o], v[o + 1], v[o + 2], a);
  const float4 r = dstep(w2[0], w2[1], w2[2], a);

  *(float4*)(out + base) = r;
  if constexpr (WB16) {
    *(short4*)(bfout + base) = make_short4(f2b(r.x), f2b(r.y), f2b(r.z), f2b(r.w));
  }
}

// ---------------------------------------------------------------------------
// LN helper + sample/LN1
// ---------------------------------------------------------------------------
__device__ __forceinline__ void ln_stats_512(float sum, float sq, float& mu, float& inv_std) {
  #pragma unroll
  for (int off = 32; off >= 1; off >>= 1) {
    sum += __shfl_down(sum, off);
    sq  += __shfl_down(sq,  off);
  }
  __shared__ float red[8];
  __shared__ float mv[2];
  const int lane = threadIdx.x & 63;
  const int wid = threadIdx.x >> 6;
  if (lane == 0) { red[wid] = sum; red[4 + wid] = sq; }
  __syncthreads();
  if (threadIdx.x == 0) {
    float ts = red[0] + red[1] + red[2] + red[3];
    float tq = red[4] + red[5] + red[6] + red[7];
    float m = ts * (1.0f / 512.0f);
    float v = tq * (1.0f / 512.0f) - m * m;
    mv[0] = m;
    mv[1] = rsqrtf(v + 1e-5f);
  }
  __syncthreads();
  mu = mv[0];
  inv_std = mv[1];
}

__global__ __launch_bounds__(256) void sample_ln_kernel(
    const float* __restrict__ field, const float* __restrict__ pos,
    const float* __restrict__ emb, const float* __restrict__ g,
    const float* __restrict__ be, short* __restrict__ enhb)
{
  const size_t row = blockIdx.x;
  const int b = (int)(row >> 11);
  const int t = threadIdx.x;

  const float p = pos[row];
  const float u = fminf(fmaxf(p, 0.0f), 1.0f) * 511.0f;
  int i0 = (int)floorf(u);
  if (i0 > MM - 2) i0 = MM - 2;
  if (i0 < 0) i0 = 0;
  const float w = u - (float)i0;

  const float* f0 = field + ((size_t)b * MM + i0) * DD;
  const int j = t * 2;
  const float2 a0 = *(const float2*)(f0 + j);
  const float2 a1 = *(const float2*)(f0 + DD + j);
  const float2 e = *(const float2*)(emb + row * DD + j);
  const float sx = (1.0f - w) * a0.x + w * a1.x + e.x;
  const float sy = (1.0f - w) * a0.y + w * a1.y + e.y;

  float mu, is;
  ln_stats_512(sx + sy, sx * sx + sy * sy, mu, is);

  const float2 gg = *(const float2*)(g + j);
  const float2 bb2 = *(const float2*)(be + j);
  *(short2*)&enhb[row * DD + j] = make_short2(
      f2b((sx - mu) * is * gg.x + bb2.x),
      f2b((sy - mu) * is * gg.y + bb2.y));
}

// ---------------------------------------------------------------------------

extern "C" void kernel_launch(void* const* d_in, const int* in_sizes, int n_in,
                              void* d_out, int out_size, void* d_ws, size_t ws_size,
                              hipStream_t stream)
{
  const float* emb   = (const float*)d_in[0];
  const float* pos   = (const float*)d_in[1];
  const float* sigma = (const float*)d_in[2];
  const float* alpha = (const float*)d_in[3];
  const float* w_int = (const float*)d_in[4];
  const float* b_int = (const float*)d_in[5];
  const float* diffc = (const float*)d_in[6];
  const float* W1    = (const float*)d_in[7];
  const float* b1    = (const float*)d_in[8];
  const float* W2    = (const float*)d_in[9];
  const float* b2    = (const float*)d_in[10];
  const float* evoc  = (const float*)d_in[11];
  const float* ln1g  = (const float*)d_in[12];
  const float* ln1b  = (const float*)d_in[13];
  const float* Wout  = (const float*)d_in[14];
  const float* bout  = (const float*)d_in[15];
  const float* ln2g  = (const float*)d_in[16];
  const float* ln2b  = (const float*)d_in[17];

  float* out = (float*)d_out;
  char* w = (char*)d_ws;
  // ws map (bytes), total 86.0 MB:
  //   f0   [0,        16.78M)  fp32 field ping
  //   Kmat [16.78M,   50.33M)  bf16 [B][M][N]     dead after RBF GEMM
  //   f1   [16.78M,   33.55M)  overlays Kmat lo   first write: diffuse3 #1
  //   mixb [33.55M,   41.94M)  overlays Kmat mid  first write: mix_kernel
  //   hb   [41.94M,   50.33M)  overlays Kmat hi   first write: W1 GEMM
  //   embT [50.33M,   83.89M)  bf16 [B][D][N]     dead after RBF GEMM
  //   enhb [50.33M,   83.89M)  overlays embT      first write: sample_ln
  //   wT   [83.89M,   85.98M)  4x 512x512 bf16 (woutT has +I)
  float* f0    = (float*)w;
  short* Kmat  = (short*)(w + 16777216);
  float* f1    = (float*)(w + 16777216);
  short* mixb  = (short*)(w + 33554432);
  short* hb    = (short*)(w + 41943040);
  short* embT  = (short*)(w + 50331648);
  short* enhb  = (short*)(w + 50331648);
  short* wT    = (short*)(w + 83886080);
  short* wintT = wT;
  short* w1T   = wT + (size_t)DD * DD;
  short* w2T   = wT + (size_t)2 * DD * DD;
  short* woutT = wT + (size_t)3 * DD * DD;

  const dim3 blk(256);
  const int diff_blocks = BB * MM * DD / 4 / 256;  // 4096

  // 0) transposes + Kmat
  wtrans_kernel<<<dim3(16, 16, 4), blk, 0, stream>>>(w_int, W1, W2, Wout, wT);
  embtrans_kernel<<<dim3(64, 16, 16), blk, 0, stream>>>(emb, embT);
  kmat_kernel<<<dim3(BB * MM * NN / 8 / 256), blk, 0, stream>>>(pos, sigma, Kmat);

  // 1) RBF projection (batch-major grid for XCD L2 locality)
  gemm_mfma<64, 128, 256, 1, 4, 0, 0, false, true, false, true>
      <<<dim3(BB, MM / 64, DD / 128), blk, 0, stream>>>(
          Kmat, embT, nullptr, nullptr, f0, nullptr, NN);

  // 2) head mix -> mixb ; field += mix@w_int + b_int (in place f0)
  mix_kernel<<<dim3(BB * MM), blk, 0, stream>>>(f0, alpha, mixb);
  gemm_mfma<64, 128, 256, 1, 4, 0, 1, true, true, false, false>
      <<<dim3(BB * MM / 64, DD / 128), blk, 0, stream>>>(
          mixb, wintT, b_int, f0, f0, nullptr, DD);

  // 3) diffusion chain 1: f0 -> f1 (+ bf16 copy into mixb for MLP A)
  diffuse3_kernel<true><<<dim3(diff_blocks), blk, 0, stream>>>(f0, f1, diffc, mixb);

  // 4) MLP: hb = gelu(field@W1+b1) ; field = hb@W2 + b2 + field (f1)
  gemm_mfma<64, 128, 256, 1, 4, 1, 0, true, false, true, false>
      <<<dim3(BB * MM / 64, DD / 128), blk, 0, stream>>>(
          mixb, w1T, b1, nullptr, nullptr, hb, DD);
  gemm_mfma<64, 128, 256, 1, 4, 0, 1, true, true, false, false>
      <<<dim3(BB * MM / 64, DD / 128), blk, 0, stream>>>(
          hb, w2T, b2, f1, f1, nullptr, DD);

  // 5) diffusion chain 2: f1 -> f0
  diffuse3_kernel<false><<<dim3(diff_blocks), blk, 0, stream>>>(f1, f0, evoc, nullptr);

  // 6+7a) sample + residual + LN1 -> enhb (bf16)
  sample_ln_kernel<<<dim3(BB * NN), blk, 0, stream>>>(f0, pos, emb, ln1g, ln1b, enhb);

  // 7b) out = LN2( enh@(Wout+I) + bout )  — fused GEMM+LN
  gemm_out_ln<<<dim3(BB * NN / 64), dim3(512), 0, stream>>>(
      enhb, woutT, bout, ln2g, ln2b, out);
}

// Round 6
// 334.722 us; speedup vs baseline: 2.8016x; 1.0395x over previous
//
#include <hip/hip_runtime.h>
#include <hip/hip_bf16.h>
#include <math.h>

#define BB 16
#define NN 2048
#define DD 512
#define MM 512

typedef __attribute__((ext_vector_type(8))) short bf16x8;
typedef __attribute__((ext_vector_type(4))) float f32x4;

__device__ __forceinline__ short f2b(float x) {
  union { __hip_bfloat16 h; short s; } u; u.h = __float2bfloat16(x); return u.s;
}
__device__ __forceinline__ float b2f(short s) {
  union { short s2; __hip_bfloat16 h; } u; u.s2 = s; return __bfloat162float(u.h);
}
__device__ __forceinline__ float gelu_f(float x) {
  float x3 = x * x * x;
  return 0.5f * x * (1.0f + tanhf(0.79788456080286536f * (x + 0.044715f * x3)));
}

// ---------------------------------------------------------------------------
// Generic bf16 MFMA GEMM, 2-phase double-buffered.
// A: [R][K] bf16 row-major; BT: [Ncols][K] bf16 (k-contiguous).
// mfma_f32_16x16x32_bf16: A/B frag idx=lane&15, k=(lane>>4)*8+0..7;
// C/D frag col=lane&15, row=(lane>>4)*4+reg  [verified m89/m91]
// ---------------------------------------------------------------------------
template<int BM, int BN, int NT, int WR, int WC, int ACT, int RES,
         bool BIAS, bool WB32, bool WB16, bool BATCH>
__global__ __launch_bounds__(NT) void gemm_mfma(
    const short* __restrict__ A, const short* __restrict__ BT,
    const float* __restrict__ bias, const void* __restrict__ res,
    float* __restrict__ C, short* __restrict__ Cb, int K)
{
  constexpr int WAVES = NT / 64;
  constexpr int MF = BM / WR / 16;
  constexpr int NF = BN / WC / 16;
  constexpr int WMT = BM / WR;
  constexpr int WNT = BN / WC;
  constexpr int CHA = BM / 16;
  constexpr int CHB = BN / 16;

  __shared__ short As[2][BM * 32];
  __shared__ short Bs[2][BN * 32];

  const int tid = threadIdx.x;
  const int wid = tid >> 6, lane = tid & 63;
  const int lrow = lane & 15, kg = lane >> 4;
  const int wr = (WR == 1) ? 0 : (wid >> 1);
  const int wc = (WR == 1) ? wid : (wid & 1);

  int r0, c0, z;
  if constexpr (BATCH) {
    z = blockIdx.x; r0 = blockIdx.y * BM; c0 = blockIdx.z * BN;
  } else {
    z = 0; r0 = blockIdx.x * BM; c0 = blockIdx.y * BN;
  }
  const size_t zA  = BATCH ? (size_t)z * MM * K : 0;
  const size_t zBT = BATCH ? (size_t)z * DD * K : 0;
  const size_t zC  = BATCH ? (size_t)z * MM * DD : 0;

  auto stage = [&](int bf, int kc) {
    #pragma unroll
    for (int i = 0; i < CHB / WAVES; ++i) {
      const int ch = wid * (CHB / WAVES) + i;
      const int col = ch * 16 + (lane >> 2);
      const short* gp = BT + zBT + (size_t)(c0 + col) * K + kc + (lane & 3) * 8;
      __builtin_amdgcn_global_load_lds(
          (const __attribute__((address_space(1))) void*)gp,
          (__attribute__((address_space(3))) void*)&Bs[bf][ch * 512], 16, 0, 0);
    }
    if constexpr (CHA >= WAVES) {
      #pragma unroll
      for (int i = 0; i < CHA / WAVES; ++i) {
        const int ch = wid * (CHA / WAVES) + i;
        const int row = ch * 16 + (lane >> 2);
        const short* gp = A + zA + (size_t)(r0 + row) * K + kc + (lane & 3) * 8;
        __builtin_amdgcn_global_load_lds(
            (const __attribute__((address_space(1))) void*)gp,
            (__attribute__((address_space(3))) void*)&As[bf][ch * 512], 16, 0, 0);
      }
    } else {
      if (wid < CHA) {
        const int row = wid * 16 + (lane >> 2);
        const short* gp = A + zA + (size_t)(r0 + row) * K + kc + (lane & 3) * 8;
        __builtin_amdgcn_global_load_lds(
            (const __attribute__((address_space(1))) void*)gp,
            (__attribute__((address_space(3))) void*)&As[bf][wid * 512], 16, 0, 0);
      }
    }
  };

  f32x4 acc[MF][NF];
  #pragma unroll
  for (int m = 0; m < MF; ++m)
    #pragma unroll
    for (int n = 0; n < NF; ++n) acc[m][n] = (f32x4){0.f, 0.f, 0.f, 0.f};

  stage(0, 0);
  __syncthreads();

  int buf = 0;
  for (int kc = 0; kc < K; kc += 32) {
    if (kc + 32 < K) stage(buf ^ 1, kc + 32);

    bf16x8 af[MF], bfv[NF];
    #pragma unroll
    for (int m = 0; m < MF; ++m)
      af[m] = *(const bf16x8*)&As[buf][(wr * WMT + m * 16 + lrow) * 32 + kg * 8];
    #pragma unroll
    for (int n = 0; n < NF; ++n)
      bfv[n] = *(const bf16x8*)&Bs[buf][(wc * WNT + n * 16 + lrow) * 32 + kg * 8];
    #pragma unroll
    for (int m = 0; m < MF; ++m)
      #pragma unroll
      for (int n = 0; n < NF; ++n)
        acc[m][n] = __builtin_amdgcn_mfma_f32_16x16x32_bf16(af[m], bfv[n], acc[m][n], 0, 0, 0);

    __syncthreads();
    buf ^= 1;
  }

  #pragma unroll
  for (int m = 0; m < MF; ++m) {
    #pragma unroll
    for (int n = 0; n < NF; ++n) {
      const int col = c0 + wc * WNT + n * 16 + lrow;
      const int row0 = r0 + wr * WMT + m * 16 + kg * 4;
      float bi = 0.0f;
      if constexpr (BIAS) bi = bias[col];
      #pragma unroll
      for (int r = 0; r < 4; ++r) {
        float x = acc[m][n][r] + bi;
        if constexpr (ACT == 1) x = gelu_f(x);
        const size_t off = zC + (size_t)(row0 + r) * DD + col;
        if constexpr (RES == 1) x += ((const float*)res)[off];
        if constexpr (RES == 2) x += b2f(((const short*)res)[off]);
        if constexpr (WB32) C[off] = x;
        if constexpr (WB16) Cb[off] = f2b(x);
      }
    }
  }
}

// ---------------------------------------------------------------------------
// Output GEMM fused with LN2, BM=128 x BN=512, 1024 threads (16 waves, 2x8).
// Full rows in-block -> LN2 in epilogue. Residual folded into Wout+I.
// MFMA:staged = 256 MFMA / 40KB per K-step (2x round-5 intensity).
// grid 256 = 1 block/CU, 4 waves/SIMD.
// ---------------------------------------------------------------------------
__global__ __launch_bounds__(1024) void gemm_out_ln(
    const short* __restrict__ A, const short* __restrict__ BT,
    const float* __restrict__ bias, const float* __restrict__ g,
    const float* __restrict__ be, float* __restrict__ out)
{
  constexpr int BM = 128, BN = 512, K = 512;
  constexpr int WAVES = 16, CHB = BN / 16, CHA = BM / 16;

  __shared__ short As[2][BM * 32];    // 16 KB
  __shared__ short Bs[2][BN * 32];    // 64 KB
  __shared__ float redS[8][BM];       // 4 KB
  __shared__ float redQ[8][BM];       // 4 KB
  __shared__ float lnMu[BM], lnIs[BM];

  const int tid = threadIdx.x;
  const int wid = tid >> 6, lane = tid & 63;
  const int lrow = lane & 15, kg = lane >> 4;
  const int wr = wid >> 3;            // 0..1 (64 rows each)
  const int wc = wid & 7;             // 0..7 (64 cols each)
  const int r0 = blockIdx.x * BM;

  auto stage = [&](int bf, int kc) {
    #pragma unroll
    for (int i = 0; i < CHB / WAVES; ++i) {
      const int ch = wid * (CHB / WAVES) + i;
      const int col = ch * 16 + (lane >> 2);
      const short* gp = BT + (size_t)col * K + kc + (lane & 3) * 8;
      __builtin_amdgcn_global_load_lds(
          (const __attribute__((address_space(1))) void*)gp,
          (__attribute__((address_space(3))) void*)&Bs[bf][ch * 512], 16, 0, 0);
    }
    if (wid < CHA) {
      const int row = wid * 16 + (lane >> 2);
      const short* gp = A + (size_t)(r0 + row) * K + kc + (lane & 3) * 8;
      __builtin_amdgcn_global_load_lds(
          (const __attribute__((address_space(1))) void*)gp,
          (__attribute__((address_space(3))) void*)&As[bf][wid * 512], 16, 0, 0);
    }
  };

  f32x4 acc[4][4];
  #pragma unroll
  for (int m = 0; m < 4; ++m)
    #pragma unroll
    for (int n = 0; n < 4; ++n) acc[m][n] = (f32x4){0.f, 0.f, 0.f, 0.f};

  stage(0, 0);
  __syncthreads();
  int buf = 0;
  for (int kc = 0; kc < K; kc += 32) {
    if (kc + 32 < K) stage(buf ^ 1, kc + 32);
    bf16x8 af[4], bfv[4];
    #pragma unroll
    for (int m = 0; m < 4; ++m)
      af[m] = *(const bf16x8*)&As[buf][(wr * 64 + m * 16 + lrow) * 32 + kg * 8];
    #pragma unroll
    for (int n = 0; n < 4; ++n)
      bfv[n] = *(const bf16x8*)&Bs[buf][(wc * 64 + n * 16 + lrow) * 32 + kg * 8];
    #pragma unroll
    for (int m = 0; m < 4; ++m)
      #pragma unroll
      for (int n = 0; n < 4; ++n)
        acc[m][n] = __builtin_amdgcn_mfma_f32_16x16x32_bf16(af[m], bfv[n], acc[m][n], 0, 0, 0);
    __syncthreads();
    buf ^= 1;
  }

  // bias, then per-row LN stats (reduce over n-frags, 16 lrow lanes, 8 wc waves)
  #pragma unroll
  for (int m = 0; m < 4; ++m) {
    #pragma unroll
    for (int n = 0; n < 4; ++n) {
      const float bi = bias[wc * 64 + n * 16 + lrow];
      #pragma unroll
      for (int r = 0; r < 4; ++r) acc[m][n][r] += bi;
    }
  }
  #pragma unroll
  for (int m = 0; m < 4; ++m) {
    #pragma unroll
    for (int r = 0; r < 4; ++r) {
      float ps = acc[m][0][r] + acc[m][1][r] + acc[m][2][r] + acc[m][3][r];
      float pq = acc[m][0][r] * acc[m][0][r] + acc[m][1][r] * acc[m][1][r] +
                 acc[m][2][r] * acc[m][2][r] + acc[m][3][r] * acc[m][3][r];
      #pragma unroll
      for (int off = 8; off >= 1; off >>= 1) {
        ps += __shfl_xor(ps, off);
        pq += __shfl_xor(pq, off);
      }
      if (lrow == 0) {
        const int row = wr * 64 + m * 16 + kg * 4 + r;
        redS[wc][row] = ps;
        redQ[wc][row] = pq;
      }
    }
  }
  __syncthreads();
  if (tid < BM) {
    float s = 0.f, q = 0.f;
    #pragma unroll
    for (int w = 0; w < 8; ++w) { s += redS[w][tid]; q += redQ[w][tid]; }
    const float mu = s * (1.0f / 512.0f);
    const float var = q * (1.0f / 512.0f) - mu * mu;
    lnMu[tid] = mu;
    lnIs[tid] = rsqrtf(var + 1e-5f);
  }
  __syncthreads();
  #pragma unroll
  for (int m = 0; m < 4; ++m) {
    #pragma unroll
    for (int n = 0; n < 4; ++n) {
      const int col = wc * 64 + n * 16 + lrow;
      const float gc = g[col], bc = be[col];
      #pragma unroll
      for (int r = 0; r < 4; ++r) {
        const int row = wr * 64 + m * 16 + kg * 4 + r;
        out[(size_t)(r0 + row) * DD + col] =
            (acc[m][n][r] - lnMu[row]) * lnIs[row] * gc + bc;
      }
    }
  }
}

// ---------------------------------------------------------------------------
// Weff = I + A_mix @ w_int, written TRANSPOSED bf16: WeffT[c][q].
// A_mix[q,c']: mix+proj fold — (field@Weff)[c] == field[c] + (mix@w_int)[c].
// WeffT[c][q] = (q==c) + sum_h alpha[h][q>>6] * w_int[h*64+(q&63)][c]
// grid (16,16): bx=q-tile, by=c-tile; 32x32 tiles via LDS transpose.
// ---------------------------------------------------------------------------
__global__ __launch_bounds__(256) void weff_kernel(
    const float* __restrict__ alpha, const float* __restrict__ w_int,
    short* __restrict__ WeffT)
{
  __shared__ float tle[32][33];
  const int q0 = blockIdx.x * 32;
  const int c0 = blockIdx.y * 32;
  const int t = threadIdx.x;
  const int r = t >> 3, c4 = (t & 7) * 4;   // r: q-offset, c4: c-offset
  const int kq = q0 >> 6;
  const int jb = q0 & 63;

  float v[4] = {0.f, 0.f, 0.f, 0.f};
  #pragma unroll
  for (int h = 0; h < 8; ++h) {
    const float a = alpha[h * 8 + kq];
    const float4 wv = *(const float4*)(w_int + (size_t)(h * 64 + jb + r) * DD + c0 + c4);
    v[0] += a * wv.x; v[1] += a * wv.y; v[2] += a * wv.z; v[3] += a * wv.w;
  }
  #pragma unroll
  for (int j = 0; j < 4; ++j) {
    if (q0 + r == c0 + c4 + j) v[j] += 1.0f;
    tle[r][c4 + j] = v[j];
  }
  __syncthreads();
  const short4 o = make_short4(f2b(tle[c4 + 0][r]), f2b(tle[c4 + 1][r]),
                               f2b(tle[c4 + 2][r]), f2b(tle[c4 + 3][r]));
  *(short4*)(WeffT + (size_t)(c0 + r) * DD + q0 + c4) = o;
}

// ---------------------------------------------------------------------------
// Weight transpose fp32->bf16 for W1, W2, Wout: WT[c][k] = W[k][c];
// z==2 (Wout) adds +I (residual fold).
// ---------------------------------------------------------------------------
__global__ __launch_bounds__(256) void wtrans_kernel(
    const float* __restrict__ w1, const float* __restrict__ w2,
    const float* __restrict__ w3, short* __restrict__ outW)
{
  __shared__ float tle[32][33];
  const int z = blockIdx.z;
  const float* W = (z == 0) ? w1 : (z == 1) ? w2 : w3;
  short* WT = outW + (size_t)(z + 1) * DD * DD;
  const int bx = blockIdx.x * 32;   // k tile
  const int by = blockIdx.y * 32;   // c tile
  const int t = threadIdx.x;
  const int r = t >> 3, c4 = (t & 7) * 4;
  const float4 v = *(const float4*)(W + (size_t)(bx + r) * DD + by + c4);
  tle[r][c4 + 0] = v.x; tle[r][c4 + 1] = v.y; tle[r][c4 + 2] = v.z; tle[r][c4 + 3] = v.w;
  __syncthreads();
  short4 o;
  #pragma unroll
  for (int j = 0; j < 4; ++j) {
    float val = tle[c4 + j][r];
    if (z == 2 && (bx + c4 + j) == (by + r)) val += 1.0f;
    ((short*)&o)[j] = f2b(val);
  }
  *(short4*)(WT + (size_t)(by + r) * DD + bx + c4) = o;
}

// emb [b][n][d] fp32 -> embT [b][d][n] bf16
__global__ __launch_bounds__(256) void embtrans_kernel(
    const float* __restrict__ emb, short* __restrict__ embT)
{
  __shared__ float tle[32][33];
  const int z = blockIdx.z;
  const int bx = blockIdx.x * 32;  // n tile
  const int by = blockIdx.y * 32;  // d tile
  const int t = threadIdx.x;
  const int r = t >> 3, c4 = (t & 7) * 4;
  const float4 v = *(const float4*)(emb + ((size_t)z * NN + bx + r) * DD + by + c4);
  tle[r][c4 + 0] = v.x; tle[r][c4 + 1] = v.y; tle[r][c4 + 2] = v.z; tle[r][c4 + 3] = v.w;
  __syncthreads();
  const short4 o = make_short4(f2b(tle[c4 + 0][r]), f2b(tle[c4 + 1][r]),
                               f2b(tle[c4 + 2][r]), f2b(tle[c4 + 3][r]));
  *(short4*)(embT + ((size_t)z * DD + by + r) * NN + bx + c4) = o;
}

// ---------------------------------------------------------------------------
// Kmat precompute: Kmat[b][m][n] = exp(-(g_m - p_bn)^2 / (2 sigma^2)) bf16
// ---------------------------------------------------------------------------
__global__ __launch_bounds__(256) void kmat_kernel(
    const float* __restrict__ pos, const float* __restrict__ sigp,
    short* __restrict__ Kmat)
{
  const int gid = blockIdx.x * 256 + threadIdx.x;
  const int n8 = gid & 255;
  const int m  = (gid >> 8) & (MM - 1);
  const int b  = gid >> 17;
  const float s = sigp[0];
  const float inv2s2 = 1.0f / (2.0f * s * s);
  const float g = (float)m * (1.0f / 511.0f);
  const float* pp = pos + (size_t)b * NN + n8 * 8;
  const float4 p0 = *(const float4*)pp;
  const float4 p1 = *(const float4*)(pp + 4);
  const float pv[8] = {p0.x, p0.y, p0.z, p0.w, p1.x, p1.y, p1.z, p1.w};
  bf16x8 o;
  #pragma unroll
  for (int j = 0; j < 8; ++j) {
    const float d = g - pv[j];
    o[j] = f2b(__expf(-(d * d) * inv2s2));
  }
  *(bf16x8*)&Kmat[((size_t)b * MM + m) * NN + n8 * 8] = o;
}

// ---------------------------------------------------------------------------
// Fused 3-step diffusion (7-row clamped window, 3 Euler steps in registers)
// ---------------------------------------------------------------------------
__device__ __forceinline__ float4 dstep(float4 fm, float4 f, float4 fp, float4 a) {
  float4 o;
  o.x = f.x + a.x * (fm.x - 2.0f * f.x + fp.x);
  o.y = f.y + a.y * (fm.y - 2.0f * f.y + fp.y);
  o.z = f.z + a.z * (fm.z - 2.0f * f.z + fp.z);
  o.w = f.w + a.w * (fm.w - 2.0f * f.w + fp.w);
  return o;
}

template<bool WB16>
__global__ __launch_bounds__(256) void diffuse3_kernel(
    const float* __restrict__ in, float* __restrict__ out,
    const float* __restrict__ coef, short* __restrict__ bfout)
{
  const size_t base = ((size_t)blockIdx.x * 256 + threadIdx.x) * 4;
  const int d = (int)(base & (DD - 1));
  const int m = (int)((base >> 9) & (MM - 1));
  const size_t rowbase = base - (size_t)m * DD;

  float4 u[7];
  #pragma unroll
  for (int o = 0; o < 7; ++o) {
    int mm = m + o - 3;
    mm = mm < 0 ? 0 : (mm > MM - 1 ? MM - 1 : mm);
    u[o] = *(const float4*)(in + rowbase + (size_t)mm * DD);
  }
  const float4 c = *(const float4*)(coef + d);
  float4 a;
  a.x = 0.01f * c.x; a.y = 0.01f * c.y; a.z = 0.01f * c.z; a.w = 0.01f * c.w;

  float4 v[5];
  #pragma unroll
  for (int o = 0; o < 5; ++o) v[o] = dstep(u[o], u[o + 1], u[o + 2], a);
  float4 w2[3];
  #pragma unroll
  for (int o = 0; o < 3; ++o) w2[o] = dstep(v[o], v[o + 1], v[o + 2], a);
  const float4 r = dstep(w2[0], w2[1], w2[2], a);

  *(float4*)(out + base) = r;
  if constexpr (WB16) {
    *(short4*)(bfout + base) = make_short4(f2b(r.x), f2b(r.y), f2b(r.z), f2b(r.w));
  }
}

// ---------------------------------------------------------------------------
// LN helper + sample/LN1
// ---------------------------------------------------------------------------
__device__ __forceinline__ void ln_stats_512(float sum, float sq, float& mu, float& inv_std) {
  #pragma unroll
  for (int off = 32; off >= 1; off >>= 1) {
    sum += __shfl_down(sum, off);
    sq  += __shfl_down(sq,  off);
  }
  __shared__ float red[8];
  __shared__ float mv[2];
  const int lane = threadIdx.x & 63;
  const int wid = threadIdx.x >> 6;
  if (lane == 0) { red[wid] = sum; red[4 + wid] = sq; }
  __syncthreads();
  if (threadIdx.x == 0) {
    float ts = red[0] + red[1] + red[2] + red[3];
    float tq = red[4] + red[5] + red[6] + red[7];
    float m = ts * (1.0f / 512.0f);
    float v = tq * (1.0f / 512.0f) - m * m;
    mv[0] = m;
    mv[1] = rsqrtf(v + 1e-5f);
  }
  __syncthreads();
  mu = mv[0];
  inv_std = mv[1];
}

__global__ __launch_bounds__(256) void sample_ln_kernel(
    const float* __restrict__ field, const float* __restrict__ pos,
    const float* __restrict__ emb, const float* __restrict__ g,
    const float* __restrict__ be, short* __restrict__ enhb)
{
  const size_t row = blockIdx.x;
  const int b = (int)(row >> 11);
  const int t = threadIdx.x;

  const float p = pos[row];
  const float u = fminf(fmaxf(p, 0.0f), 1.0f) * 511.0f;
  int i0 = (int)floorf(u);
  if (i0 > MM - 2) i0 = MM - 2;
  if (i0 < 0) i0 = 0;
  const float w = u - (float)i0;

  const float* f0 = field + ((size_t)b * MM + i0) * DD;
  const int j = t * 2;
  const float2 a0 = *(const float2*)(f0 + j);
  const float2 a1 = *(const float2*)(f0 + DD + j);
  const float2 e = *(const float2*)(emb + row * DD + j);
  const float sx = (1.0f - w) * a0.x + w * a1.x + e.x;
  const float sy = (1.0f - w) * a0.y + w * a1.y + e.y;

  float mu, is;
  ln_stats_512(sx + sy, sx * sx + sy * sy, mu, is);

  const float2 gg = *(const float2*)(g + j);
  const float2 bb2 = *(const float2*)(be + j);
  *(short2*)&enhb[row * DD + j] = make_short2(
      f2b((sx - mu) * is * gg.x + bb2.x),
      f2b((sy - mu) * is * gg.y + bb2.y));
}

// ---------------------------------------------------------------------------

extern "C" void kernel_launch(void* const* d_in, const int* in_sizes, int n_in,
                              void* d_out, int out_size, void* d_ws, size_t ws_size,
                              hipStream_t stream)
{
  const float* emb   = (const float*)d_in[0];
  const float* pos   = (const float*)d_in[1];
  const float* sigma = (const float*)d_in[2];
  const float* alpha = (const float*)d_in[3];
  const float* w_int = (const float*)d_in[4];
  const float* b_int = (const float*)d_in[5];
  const float* diffc = (const float*)d_in[6];
  const float* W1    = (const float*)d_in[7];
  const float* b1    = (const float*)d_in[8];
  const float* W2    = (const float*)d_in[9];
  const float* b2    = (const float*)d_in[10];
  const float* evoc  = (const float*)d_in[11];
  const float* ln1g  = (const float*)d_in[12];
  const float* ln1b  = (const float*)d_in[13];
  const float* Wout  = (const float*)d_in[14];
  const float* bout  = (const float*)d_in[15];
  const float* ln2g  = (const float*)d_in[16];
  const float* ln2b  = (const float*)d_in[17];

  float* out = (float*)d_out;
  char* w = (char*)d_ws;
  // ws map (bytes), total 94.4 MB (<= 100.7 MB proven in round 0):
  //   f0      [0,        16.78M)  fp32 field ping (first write: gemm2/Weff)
  //   Kmat    [16.78M,   50.33M)  bf16 [B][M][N]    dead after RBF GEMM
  //     f1      [16.78M, 33.55M)  overlays Kmat     first write: diffuse3 #1
  //     hb      [33.55M, 41.94M)  overlays Kmat     first write: W1 GEMM
  //     fieldb2 [41.94M, 50.33M)  overlays Kmat     first write: diffuse3 #1
  //   embT    [50.33M,   83.89M)  bf16 [B][D][N]    dead after RBF GEMM
  //     enhb    overlays embT                       first write: sample_ln
  //   wT      [83.89M,   85.98M)  WeffT, w1T, w2T, woutT(+I)
  //   fieldb  [85.98M,   94.37M)  bf16 RBF output, live until gemm2
  float* f0      = (float*)w;
  short* Kmat    = (short*)(w + 16777216);
  float* f1      = (float*)(w + 16777216);
  short* hb      = (short*)(w + 33554432);
  short* fieldb2 = (short*)(w + 41943040);
  short* embT    = (short*)(w + 50331648);
  short* enhb    = (short*)(w + 50331648);
  short* wT      = (short*)(w + 83886080);
  short* weffT   = wT;
  short* w1T     = wT + (size_t)DD * DD;
  short* w2T     = wT + (size_t)2 * DD * DD;
  short* woutT   = wT + (size_t)3 * DD * DD;
  short* fieldb  = (short*)(w + 85983232);

  const dim3 blk(256);
  const int diff_blocks = BB * MM * DD / 4 / 256;  // 4096

  // 0) Weff fold, weight transposes, emb transpose, Kmat
  weff_kernel<<<dim3(16, 16), blk, 0, stream>>>(alpha, w_int, weffT);
  wtrans_kernel<<<dim3(16, 16, 3), blk, 0, stream>>>(W1, W2, Wout, wT);
  embtrans_kernel<<<dim3(64, 16, 16), blk, 0, stream>>>(emb, embT);
  kmat_kernel<<<dim3(BB * MM * NN / 8 / 256), blk, 0, stream>>>(pos, sigma, Kmat);

  // 1) RBF projection -> fieldb (bf16 only; fp32 copy no longer needed)
  gemm_mfma<64, 128, 256, 1, 4, 0, 0, false, false, true, true>
      <<<dim3(BB, MM / 64, DD / 128), blk, 0, stream>>>(
          Kmat, embT, nullptr, nullptr, nullptr, fieldb, NN);

  // 2) field = fieldb @ Weff + b_int  (head-mix + proj + residual folded)
  gemm_mfma<64, 128, 256, 1, 4, 0, 0, true, true, false, false>
      <<<dim3(BB * MM / 64, DD / 128), blk, 0, stream>>>(
          fieldb, weffT, b_int, nullptr, f0, nullptr, DD);

  // 3) diffusion chain 1: f0 -> f1 (+ bf16 copy into fieldb2 for MLP A)
  diffuse3_kernel<true><<<dim3(diff_blocks), blk, 0, stream>>>(f0, f1, diffc, fieldb2);

  // 4) MLP: hb = gelu(field@W1+b1) ; field = hb@W2 + b2 + field (f1 in place)
  gemm_mfma<64, 128, 256, 1, 4, 1, 0, true, false, true, false>
      <<<dim3(BB * MM / 64, DD / 128), blk, 0, stream>>>(
          fieldb2, w1T, b1, nullptr, nullptr, hb, DD);
  gemm_mfma<64, 128, 256, 1, 4, 0, 1, true, true, false, false>
      <<<dim3(BB * MM / 64, DD / 128), blk, 0, stream>>>(
          hb, w2T, b2, f1, f1, nullptr, DD);

  // 5) diffusion chain 2: f1 -> f0
  diffuse3_kernel<false><<<dim3(diff_blocks), blk, 0, stream>>>(f1, f0, evoc, nullptr);

  // 6+7a) sample + residual + LN1 -> enhb (bf16)
  sample_ln_kernel<<<dim3(BB * NN), blk, 0, stream>>>(f0, pos, emb, ln1g, ln1b, enhb);

  // 7b) out = LN2( enh@(Wout+I) + bout ) — BM=128, 1024 threads, grid 256
  gemm_out_ln<<<dim3(BB * NN / 128), dim3(1024), 0, stream>>>(
      enhb, woutT, bout, ln2g, ln2b, out);
}